// Round 8
// baseline (172.099 us; speedup 1.0000x reference)
//
#include <hip/hip_runtime.h>
#include <climits>

// ---------------------------------------------------------------------------
// GCN 2-layer + graclus pooling, frontier-restricted (~8.7k nodes).
// Single full-E pass (k_bkt) buckets edges by dst>>10 (packed src|dst_local).
// Per-bucket kernels work in LDS (no per-edge device atomics, no global
// cursors). Aggregation and GEMM are SPLIT (R8): the latency-bound gather
// runs LDS-free at high occupancy with 4x unrolled MLP; the tiny GEMM keeps
// its LDS-staged W.
// ---------------------------------------------------------------------------

#define NF_CAP 40960
#define CHUNK 4096
#define MAXW 3200          // mark1 bitset words for N<=102400

__global__ void k_init(unsigned int* mark1w, unsigned char* mark2,
                       int* fidx, int* counts2, int* first, int* cnt,
                       int* gcur, int n, int nb) {
  int i = blockIdx.x * blockDim.x + threadIdx.x;
  if (i < n) { mark2[i] = 0; fidx[i] = -1; }
  if (i < MAXW) mark1w[i] = 0;
  if (i < NF_CAP) counts2[i] = 0;
  if (i < nb) first[i] = INT_MAX;
  if (i < 4) cnt[i] = 0;
  if (i < 128) gcur[i] = 0;
}

// batch is sorted => bp[c]=batch[2c] is non-decreasing; first[b] = boundary c.
__global__ void k_first(const int* __restrict__ batch, int* first, int nc) {
  int c = blockIdx.x * blockDim.x + threadIdx.x;
  if (c >= nc) return;
  int b = batch[2 * c];
  if (c == 0 || batch[2 * c - 2] != b) first[b] = c;
}

__global__ void k_sel(const int* __restrict__ first, int* sel,
                      unsigned int* mark1w, unsigned char* mark2, int nb, int nc) {
  int t = blockIdx.x * blockDim.x + threadIdx.x;
  if (t >= 2 * nb) return;
  int f = first[t >> 1];
  f = min(f, nc - 1);            // JAX gather clamps (empty-graph case)
  int node = 2 * f + (t & 1);
  sel[t] = node;
  atomicOr(&mark1w[node >> 5], 1u << (node & 31));
  mark2[node] = 1;
}

// --- pass 1: bucket edges by dst>>10; LDS-sorted coalesced dump --------------
__global__ __launch_bounds__(256) void k_bkt(const int* __restrict__ src,
    const int* __restrict__ dst, const float* __restrict__ w,
    const unsigned int* __restrict__ mark1w, unsigned char* mark2,
    int* gcur, uint2* bktbuf, int cap, int e, int nwords) {
  __shared__ int scnt[128], sbase[128], sgb[128];
  __shared__ unsigned int sd[CHUNK];       // packed (src<<10)|dst_local
  __shared__ float sw[CHUNK];
  __shared__ unsigned char sbk[CHUNK];     // bucket id per slot
  __shared__ unsigned int sm1[MAXW];       // mark1 bitset (12.8 KB)
  int t = threadIdx.x;
  if (t < 128) scnt[t] = 0;
  for (int j = t; j < nwords; j += 256) sm1[j] = mark1w[j];
  __syncthreads();
  int i0 = blockIdx.x * CHUNK;
  int rd[16], rs[16];
  float rw[16];
#pragma unroll
  for (int k = 0; k < 16; ++k) {
    int i = i0 + t + k * 256;
    if (i < e) {
      int d = dst[i];
      int s = src[i];
      rd[k] = d; rs[k] = s; rw[k] = w[i];
      atomicAdd(&scnt[d >> 10], 1);
      if ((sm1[d >> 5] >> (d & 31)) & 1u) mark2[s] = 1;   // src of selected
    } else {
      rd[k] = -1;
    }
  }
  __syncthreads();
  // exclusive scan of scnt[0..127]
  if (t < 128) sbase[t] = scnt[t];
  __syncthreads();
  for (int off = 1; off < 128; off <<= 1) {
    int a = (t < 128 && t >= off) ? sbase[t - off] : 0;
    __syncthreads();
    if (t < 128) sbase[t] += a;
    __syncthreads();
  }
  if (t < 128) {
    int c = scnt[t];
    sbase[t] -= c;
    sgb[t] = c ? atomicAdd(&gcur[t], c) : 0;   // <=128 device atomics / block
  }
  __syncthreads();
  if (t < 128) scnt[t] = 0;
  __syncthreads();
#pragma unroll
  for (int k = 0; k < 16; ++k) {
    if (rd[k] >= 0) {
      int b = rd[k] >> 10;
      int pos = atomicAdd(&scnt[b], 1) + sbase[b];
      sd[pos] = ((unsigned int)rs[k] << 10) | (unsigned int)(rd[k] & 1023);
      sw[pos] = rw[k];
      sbk[pos] = (unsigned char)b;
    }
  }
  __syncthreads();
  int tot = min(CHUNK, e - i0);
  for (int j = t; j < tot; j += 256) {
    int b = sbk[j];
    int gi = b * cap + sgb[b] + (j - sbase[b]);
    bktbuf[gi] = make_uint2(sd[j], __float_as_uint(sw[j]));
  }
}

__global__ void k_compact(const unsigned char* __restrict__ mark2, int* list,
                          int* fidx, int* cntF, int n) {
  int i = blockIdx.x * blockDim.x + threadIdx.x;
  if (i < n && mark2[i]) {
    int p = atomicAdd(cntF, 1);
    if (p < NF_CAP) { list[p] = i; fidx[i] = p; }
  }
}

// --- pass 2a: per-bucket degree + per-node frontier match counts (LDS) -------
__global__ __launch_bounds__(1024) void k_degB(const int* __restrict__ gcur,
    const uint2* __restrict__ bktbuf, int cap, const int* __restrict__ fidx,
    float* dinv, int* counts2, int n) {
  __shared__ float acc[1024];
  __shared__ int sfidx[1024];
  __shared__ int scount[1024];
  int t = threadIdx.x, b = blockIdx.x;
  int gbase = b << 10;
  acc[t] = 0.f;
  scount[t] = 0;
  sfidx[t] = (gbase + t < n) ? fidx[gbase + t] : -1;
  __syncthreads();
  int m = min(gcur[b], cap);
  const uint2* base = bktbuf + (size_t)b * cap;
  for (int j = t; j < m; j += 1024) {
    uint2 u = base[j];
    int dl = (int)(u.x & 1023u);
    atomicAdd(&acc[dl], __uint_as_float(u.y));    // LDS fp32 atomic
    if (sfidx[dl] >= 0) atomicAdd(&scount[dl], 1);
  }
  __syncthreads();
  int i = gbase + t;
  if (i < n) {
    dinv[i] = rsqrtf(1.0f + acc[t]);              // +1 = self-loop
    int f = sfidx[t];
    if (f >= 0) counts2[f] = scount[t];           // exclusive owner: no atomic
  }
}

// --- exclusive scan over frontier counts (single block) ----------------------
__global__ __launch_bounds__(1024) void k_scanF(const int* __restrict__ counts2,
                                                const int* __restrict__ cntF,
                                                int* frowptr) {
  __shared__ int sd[1024];
  __shared__ int carry;
  int t = threadIdx.x;
  int nf = min(*cntF, NF_CAP);
  if (t == 0) carry = 0;
  __syncthreads();
  for (int base = 0; base < nf; base += 1024) {
    int i = base + t;
    int v = (i < nf) ? counts2[i] : 0;
    sd[t] = v; __syncthreads();
    for (int off = 1; off < 1024; off <<= 1) {
      int a = (t >= off) ? sd[t - off] : 0;
      __syncthreads();
      sd[t] += a;
      __syncthreads();
    }
    int c = carry;
    if (i < nf) frowptr[i] = c + sd[t] - v;
    __syncthreads();
    if (t == 1023) carry = c + sd[t];
    __syncthreads();
  }
  if (t == 0) frowptr[nf] = carry;
}

// --- pass 2b: scatter matched edges straight into frontier CSR ---------------
__global__ __launch_bounds__(1024) void k_scat2(const int* __restrict__ gcur,
    const uint2* __restrict__ bktbuf, int cap, const int* __restrict__ fidx,
    const int* __restrict__ frowptr, const float* __restrict__ dinv,
    int* fcols, float* fvals, int n) {
  __shared__ int sfidx[1024];
  __shared__ int lcur[1024];
  int t = threadIdx.x, b = blockIdx.x;
  int gbase = b << 10;
  int f = (gbase + t < n) ? fidx[gbase + t] : -1;
  sfidx[t] = f;
  lcur[t] = (f >= 0) ? frowptr[f] : 0;
  __syncthreads();
  int m = min(gcur[b], cap);
  const uint2* base = bktbuf + (size_t)b * cap;
  for (int j = t; j < m; j += 1024) {
    uint2 u = base[j];
    int dl = (int)(u.x & 1023u);
    if (sfidx[dl] >= 0) {
      int pos = atomicAdd(&lcur[dl], 1);          // LDS cursor, no global atomics
      int s = (int)(u.x >> 10);
      fcols[pos] = s;
      fvals[pos] = dinv[s] * __uint_as_float(u.y);   // dst-side dinv in k_agg
    }
  }
}

// --- aggregation of raw x at frontier rows: LDS-free, 4x unrolled gathers ----
__global__ __launch_bounds__(256) void k_agg(const float* __restrict__ x,
    const int* __restrict__ list, const int* __restrict__ cntF,
    const int* __restrict__ frowptr, const int* __restrict__ fcols,
    const float* __restrict__ fvals, const float* __restrict__ dinv,
    float* __restrict__ aggx) {
  int lane = threadIdx.x & 63;
  int wid = (blockIdx.x * blockDim.x + threadIdx.x) >> 6;
  int nw = (gridDim.x * blockDim.x) >> 6;
  int m = min(*cntF, NF_CAP);
  const float2* x2 = (const float2*)x;
  float2* a2 = (float2*)aggx;
  for (int li = wid; li < m; li += nw) {
    int i = list[li];
    float dv = dinv[i];
    float2 xi = x2[(size_t)i * 64 + lane];
    float ax = 0.f, ay = 0.f;
    int beg = frowptr[li], end = frowptr[li + 1];
    int p = beg;
    for (; p + 4 <= end; p += 4) {
      int c0 = fcols[p], c1 = fcols[p + 1], c2 = fcols[p + 2], c3 = fcols[p + 3];
      float v0 = fvals[p], v1 = fvals[p + 1], v2 = fvals[p + 2], v3 = fvals[p + 3];
      float2 g0 = x2[(size_t)c0 * 64 + lane];     // 4 independent gathers in
      float2 g1 = x2[(size_t)c1 * 64 + lane];     // flight per wave
      float2 g2 = x2[(size_t)c2 * 64 + lane];
      float2 g3 = x2[(size_t)c3 * 64 + lane];
      ax += v0 * g0.x + v1 * g1.x + v2 * g2.x + v3 * g3.x;
      ay += v0 * g0.y + v1 * g1.y + v2 * g2.y + v3 * g3.y;
    }
    for (; p < end; ++p) {
      int c = fcols[p];
      float v = fvals[p];
      float2 g = x2[(size_t)c * 64 + lane];
      ax += v * g.x;
      ay += v * g.y;
    }
    float2 r;
    r.x = dv * (ax + dv * xi.x);
    r.y = dv * (ay + dv * xi.y);
    a2[(size_t)li * 64 + lane] = r;
  }
}

// --- tiny GEMM over compact rows: h1 = aggx @ W1 + b1 ------------------------
__global__ __launch_bounds__(256) void k_gemm1(const float* __restrict__ aggx,
    const int* __restrict__ cntF, const float* __restrict__ W1,
    const float* __restrict__ b1, float* __restrict__ h1) {
  __shared__ float Wl[128 * 64];           // 32 KB
  int t = threadIdx.x;
  for (int p = t; p < 128 * 16; p += 256)
    ((float4*)Wl)[p] = ((const float4*)W1)[p];
  __syncthreads();
  int lane = t & 63, wv = t >> 6;
  int wid = blockIdx.x * 4 + wv;
  int nw = gridDim.x * 4;
  int m = min(*cntF, NF_CAP);
  float bias = b1[lane];
  for (int r = wid; r < m; r += nw) {
    const float* a = aggx + (size_t)r * 128;
    float o = bias;
#pragma unroll
    for (int k = 0; k < 128; k += 4) {
      float4 av = *(const float4*)(a + k);   // wave-uniform broadcast
      o += av.x * Wl[(k + 0) * 64 + lane] + av.y * Wl[(k + 1) * 64 + lane] +
           av.z * Wl[(k + 2) * 64 + lane] + av.w * Wl[(k + 3) * 64 + lane];
    }
    h1[(size_t)r * 64 + lane] = o;
  }
}

// --- fused: aggregate h1 at 512 sel nodes, @W2 + b2, pairwise max, out -------
__global__ __launch_bounds__(128) void k_h2out(const float* __restrict__ h1,
    const int* __restrict__ sel, const int* __restrict__ fidx,
    const int* __restrict__ frowptr, const int* __restrict__ fcols,
    const float* __restrict__ fvals, const float* __restrict__ dinv,
    const float* __restrict__ W2, const float* __restrict__ b2,
    float* __restrict__ out, int nb) {
  __shared__ float Wl[64 * 64];
  __shared__ float sag[2][64];
  __shared__ float hh[2][64];
  int t = threadIdx.x;
  for (int p = t; p < 64 * 16; p += 128)
    ((float4*)Wl)[p] = ((const float4*)W2)[p];
  __syncthreads();
  int lane = t & 63, wv = t >> 6;
  int b = blockIdx.x;
  if (b >= nb) return;
  int node = sel[2 * b + wv];
  int f = fidx[node];
  float dv = dinv[node];
  float acc = 0.f;
  int beg = frowptr[f], end = frowptr[f + 1];
  for (int p = beg; p < end; ++p) {
    int g = fidx[fcols[p]];
    acc += fvals[p] * h1[(size_t)g * 64 + lane];
  }
  acc = dv * (acc + dv * h1[(size_t)f * 64 + lane]);
  sag[wv][lane] = acc;
  __syncthreads();
  float o = b2[lane];
#pragma unroll 8
  for (int k = 0; k < 64; ++k)
    o += sag[wv][k] * Wl[k * 64 + lane];
  hh[wv][lane] = o;
  __syncthreads();
  if (wv == 0)
    out[(size_t)b * 64 + lane] = fmaxf(hh[0][lane], hh[1][lane]);
}

extern "C" void kernel_launch(void* const* d_in, const int* in_sizes, int n_in,
                              void* d_out, int out_size, void* d_ws, size_t ws_size,
                              hipStream_t stream) {
  const float* x     = (const float*)d_in[0];
  const int*   ei    = (const int*)d_in[1];
  const float* ew    = (const float*)d_in[2];
  const int*   batch = (const int*)d_in[3];
  const float* W1    = (const float*)d_in[4];
  const float* b1    = (const float*)d_in[5];
  const float* W2    = (const float*)d_in[6];
  const float* b2    = (const float*)d_in[7];

  const int E  = in_sizes[2];
  const int N  = in_sizes[3];
  const int B  = out_size / 64;
  const int NC = N / 2;
  const int* srcI = ei;
  const int* dstI = ei + E;

  const int NBKT   = (N + 1023) >> 10;              // 98 for N=100k
  const int CAP    = ((E + NBKT - 1) / NBKT) * 2;   // ~2x expected bucket load
  const int NWORDS = (N + 31) >> 5;

  char* p = (char*)d_ws;
  auto alloc = [&](size_t bytes) -> char* {
    char* r = p;
    p += (bytes + 255) & ~size_t(255);
    return r;
  };
  float* dinv    = (float*)alloc((size_t)N * 4);
  unsigned int* mark1w = (unsigned int*)alloc((size_t)MAXW * 4);
  unsigned char* mark2 = (unsigned char*)alloc(N);
  int*   fidx    = (int*)alloc((size_t)N * 4);
  int*   list    = (int*)alloc((size_t)NF_CAP * 4);
  int*   counts2 = (int*)alloc((size_t)NF_CAP * 4);
  int*   frowptr = (int*)alloc((size_t)(NF_CAP + 1) * 4);
  int*   first   = (int*)alloc((size_t)B * 4);
  int*   sel     = (int*)alloc((size_t)2 * B * 4);
  int*   cnt     = (int*)alloc(256);                // [0]=cntF
  int*   gcur    = (int*)alloc(128 * 4);
  uint2* bktbuf  = (uint2*)alloc((size_t)NBKT * CAP * 8);
  int*   fcols   = (int*)alloc((size_t)E * 4);
  float* fvals   = (float*)alloc((size_t)E * 4);
  float* aggx    = (float*)alloc((size_t)NF_CAP * 128 * 4);
  float* h1      = (float*)alloc((size_t)NF_CAP * 64 * 4);

  int gN = (N + 255) / 256;
  int gB = (E + CHUNK - 1) / CHUNK;
  int* cntF = cnt;

  k_init<<<gN, 256, 0, stream>>>(mark1w, mark2, fidx, counts2, first, cnt, gcur, N, B);
  k_first<<<(NC + 255) / 256, 256, 0, stream>>>(batch, first, NC);
  k_sel<<<(2 * B + 255) / 256, 256, 0, stream>>>(first, sel, mark1w, mark2, B, NC);
  k_bkt<<<gB, 256, 0, stream>>>(srcI, dstI, ew, mark1w, mark2, gcur, bktbuf, CAP, E, NWORDS);
  k_compact<<<gN, 256, 0, stream>>>(mark2, list, fidx, cntF, N);
  k_degB<<<NBKT, 1024, 0, stream>>>(gcur, bktbuf, CAP, fidx, dinv, counts2, N);
  k_scanF<<<1, 1024, 0, stream>>>(counts2, cntF, frowptr);
  k_scat2<<<NBKT, 1024, 0, stream>>>(gcur, bktbuf, CAP, fidx, frowptr, dinv, fcols, fvals, N);
  k_agg<<<2048, 256, 0, stream>>>(x, list, cntF, frowptr, fcols, fvals, dinv, aggx);
  k_gemm1<<<1024, 256, 0, stream>>>(aggx, cntF, W1, b1, h1);
  k_h2out<<<B, 128, 0, stream>>>(h1, sel, fidx, frowptr, fcols, fvals, dinv, W2, b2,
                                 (float*)d_out, B);
}

// Round 9
// 155.288 us; speedup vs baseline: 1.1083x; 1.1083x over previous
//
#include <hip/hip_runtime.h>
#include <climits>

// ---------------------------------------------------------------------------
// GCN 2-layer + graclus pooling, frontier-restricted (~8.7k nodes).
//   k_bkt    : full-E pass; bucket edges by dst>>8 (391 buckets), packed
//              (src<<8|dst_local, w); frontier-src marking via L1-resident
//              mark1w bitset.
//   k_degscat: ONE bucket pass: LDS degree -> dinv, and capture edges whose
//              dst is in the frontier straight into a FIXED-STRIDE CSR
//              (frowptr[f] = f*STRIDE, no scan, raw w stored).
//   k_agg    : per-frontier-row gather of x rows (dinv[src] applied here).
//   k_gemm1  : h1 = aggx @ W1 + b1 (LDS-staged W).
//   k_h2out  : aggregate h1 at 512 sel nodes, @W2+b2, pairwise max -> out.
// No per-edge device atomics anywhere.
// ---------------------------------------------------------------------------

#define NF_CAP 40960
#define CHUNK 2048
#define STRIDE 128         // max in-degree bound (Poisson(16) -> P(>128)~0)
#define NB512 512          // padded bucket-scan width (>= NBKT=391)
#define MAXW 3200          // mark1 bitset words for N<=102400

__global__ void k_init(unsigned int* mark1w, unsigned char* mark2,
                       int* fidx, int* first, int* cnt, int* gcur,
                       int n, int nb) {
  int i = blockIdx.x * blockDim.x + threadIdx.x;
  if (i < n) { mark2[i] = 0; fidx[i] = -1; }
  if (i < MAXW) mark1w[i] = 0;
  if (i < nb) first[i] = INT_MAX;
  if (i < 4) cnt[i] = 0;
  if (i < NB512) gcur[i] = 0;
}

// batch is sorted => bp[c]=batch[2c] is non-decreasing; first[b] = boundary c.
__global__ void k_first(const int* __restrict__ batch, int* first, int nc) {
  int c = blockIdx.x * blockDim.x + threadIdx.x;
  if (c >= nc) return;
  int b = batch[2 * c];
  if (c == 0 || batch[2 * c - 2] != b) first[b] = c;
}

__global__ void k_sel(const int* __restrict__ first, int* sel,
                      unsigned int* mark1w, unsigned char* mark2, int nb, int nc) {
  int t = blockIdx.x * blockDim.x + threadIdx.x;
  if (t >= 2 * nb) return;
  int f = first[t >> 1];
  f = min(f, nc - 1);            // JAX gather clamps (empty-graph case)
  int node = 2 * f + (t & 1);
  sel[t] = node;
  atomicOr(&mark1w[node >> 5], 1u << (node & 31));
  mark2[node] = 1;
}

// --- pass 1: bucket edges by dst>>8; LDS-sorted coalesced dump ---------------
__global__ __launch_bounds__(256) void k_bkt(const int* __restrict__ src,
    const int* __restrict__ dst, const float* __restrict__ w,
    const unsigned int* __restrict__ mark1w, unsigned char* mark2,
    int* gcur, uint2* bktbuf, int cap, int e) {
  __shared__ int scnt[NB512], sbase[NB512], sgb[NB512];
  __shared__ int ssum[256];
  __shared__ unsigned int sd[CHUNK];       // packed (src<<8)|dst_local
  __shared__ float sw[CHUNK];
  __shared__ unsigned short sbk[CHUNK];    // bucket id per slot
  int t = threadIdx.x;
  scnt[2 * t] = 0; scnt[2 * t + 1] = 0;
  __syncthreads();
  int i0 = blockIdx.x * CHUNK;
  int rd[8], rs[8];
  float rw[8];
#pragma unroll
  for (int k = 0; k < 8; ++k) {
    int i = i0 + t + k * 256;
    if (i < e) {
      int d = dst[i];
      int s = src[i];
      rd[k] = d; rs[k] = s; rw[k] = w[i];
      atomicAdd(&scnt[d >> 8], 1);
      if ((mark1w[d >> 5] >> (d & 31)) & 1u) mark2[s] = 1;  // L1-resident test
    } else {
      rd[k] = -1;
    }
  }
  __syncthreads();
  // exclusive scan of scnt[0..511] with 256 threads (2 entries/thread)
  int v0 = scnt[2 * t], v1 = scnt[2 * t + 1];
  ssum[t] = v0 + v1;
  __syncthreads();
  for (int off = 1; off < 256; off <<= 1) {
    int a = (t >= off) ? ssum[t - off] : 0;
    __syncthreads();
    ssum[t] += a;
    __syncthreads();
  }
  int pbase = ssum[t] - (v0 + v1);
  sbase[2 * t] = pbase;
  sbase[2 * t + 1] = pbase + v0;
  sgb[2 * t]     = v0 ? atomicAdd(&gcur[2 * t], v0) : 0;     // <=391 dev atomics
  sgb[2 * t + 1] = v1 ? atomicAdd(&gcur[2 * t + 1], v1) : 0; // per block
  scnt[2 * t] = 0; scnt[2 * t + 1] = 0;
  __syncthreads();
#pragma unroll
  for (int k = 0; k < 8; ++k) {
    if (rd[k] >= 0) {
      int b = rd[k] >> 8;
      int pos = atomicAdd(&scnt[b], 1) + sbase[b];
      sd[pos] = ((unsigned int)rs[k] << 8) | (unsigned int)(rd[k] & 255);
      sw[pos] = rw[k];
      sbk[pos] = (unsigned short)b;
    }
  }
  __syncthreads();
  int tot = min(CHUNK, e - i0);
  for (int j = t; j < tot; j += 256) {
    int b = sbk[j];
    int off = sgb[b] + (j - sbase[b]);
    if (off < cap)
      bktbuf[(size_t)b * cap + off] = make_uint2(sd[j], __float_as_uint(sw[j]));
  }
}

__global__ void k_compact(const unsigned char* __restrict__ mark2, int* list,
                          int* fidx, int* cntF, int n) {
  int i = blockIdx.x * blockDim.x + threadIdx.x;
  if (i < n && mark2[i]) {
    int p = atomicAdd(cntF, 1);
    if (p < NF_CAP) { list[p] = i; fidx[i] = p; }
  }
}

// --- pass 2: per-bucket degree -> dinv  +  frontier-edge capture (fused) -----
__global__ __launch_bounds__(256) void k_degscat(const int* __restrict__ gcur,
    const uint2* __restrict__ bktbuf, int cap, const int* __restrict__ fidx,
    float* dinv, int* counts2, int* fcols, float* fvals, int n) {
  __shared__ float acc[256];
  __shared__ int sfidx[256];
  __shared__ int lcur[256];
  int t = threadIdx.x, b = blockIdx.x;
  int gbase = b << 8;
  acc[t] = 0.f;
  int f0 = (gbase + t < n) ? fidx[gbase + t] : -1;
  sfidx[t] = f0;
  lcur[t] = (f0 >= 0) ? f0 * STRIDE : 0;
  __syncthreads();
  int m = min(gcur[b], cap);
  const uint2* base = bktbuf + (size_t)b * cap;
  for (int j = t; j < m; j += 256) {
    uint2 u = base[j];
    int dl = (int)(u.x & 255u);
    float wv = __uint_as_float(u.y);
    atomicAdd(&acc[dl], wv);                      // LDS fp32 atomic
    int f = sfidx[dl];
    if (f >= 0) {
      int pos = atomicAdd(&lcur[dl], 1);          // LDS cursor
      if (pos < (f + 1) * STRIDE) {               // fixed-stride CSR slot
        fcols[pos] = (int)(u.x >> 8);
        fvals[pos] = wv;                          // RAW w; dinv applied later
      }
    }
  }
  __syncthreads();
  int i = gbase + t;
  if (i < n) {
    dinv[i] = rsqrtf(1.0f + acc[t]);              // +1 = self-loop
    int f = sfidx[t];
    if (f >= 0) counts2[f] = min(lcur[t] - f * STRIDE, STRIDE);
  }
}

// --- aggregation of raw x at frontier rows: LDS-free, 4x unrolled gathers ----
__global__ __launch_bounds__(256) void k_agg(const float* __restrict__ x,
    const int* __restrict__ list, const int* __restrict__ cntF,
    const int* __restrict__ counts2, const int* __restrict__ fcols,
    const float* __restrict__ fvals, const float* __restrict__ dinv,
    float* __restrict__ aggx) {
  int lane = threadIdx.x & 63;
  int wid = (blockIdx.x * blockDim.x + threadIdx.x) >> 6;
  int nw = (gridDim.x * blockDim.x) >> 6;
  int m = min(*cntF, NF_CAP);
  const float2* x2 = (const float2*)x;
  float2* a2 = (float2*)aggx;
  for (int li = wid; li < m; li += nw) {
    int i = list[li];
    float dv = dinv[i];
    float2 xi = x2[(size_t)i * 64 + lane];
    float ax = 0.f, ay = 0.f;
    int beg = li * STRIDE;
    int end = beg + counts2[li];
    int p = beg;
    for (; p + 4 <= end; p += 4) {
      int c0 = fcols[p], c1 = fcols[p + 1], c2 = fcols[p + 2], c3 = fcols[p + 3];
      float v0 = fvals[p] * dinv[c0];             // dinv broadcast-loads ride
      float v1 = fvals[p + 1] * dinv[c1];         // alongside the row gathers
      float v2 = fvals[p + 2] * dinv[c2];
      float v3 = fvals[p + 3] * dinv[c3];
      float2 g0 = x2[(size_t)c0 * 64 + lane];
      float2 g1 = x2[(size_t)c1 * 64 + lane];
      float2 g2 = x2[(size_t)c2 * 64 + lane];
      float2 g3 = x2[(size_t)c3 * 64 + lane];
      ax += v0 * g0.x + v1 * g1.x + v2 * g2.x + v3 * g3.x;
      ay += v0 * g0.y + v1 * g1.y + v2 * g2.y + v3 * g3.y;
    }
    for (; p < end; ++p) {
      int c = fcols[p];
      float v = fvals[p] * dinv[c];
      float2 g = x2[(size_t)c * 64 + lane];
      ax += v * g.x;
      ay += v * g.y;
    }
    float2 r;
    r.x = dv * (ax + dv * xi.x);
    r.y = dv * (ay + dv * xi.y);
    a2[(size_t)li * 64 + lane] = r;
  }
}

// --- tiny GEMM over compact rows: h1 = aggx @ W1 + b1 ------------------------
__global__ __launch_bounds__(256) void k_gemm1(const float* __restrict__ aggx,
    const int* __restrict__ cntF, const float* __restrict__ W1,
    const float* __restrict__ b1, float* __restrict__ h1) {
  __shared__ float Wl[128 * 64];           // 32 KB
  int t = threadIdx.x;
  for (int p = t; p < 128 * 16; p += 256)
    ((float4*)Wl)[p] = ((const float4*)W1)[p];
  __syncthreads();
  int lane = t & 63, wv = t >> 6;
  int wid = blockIdx.x * 4 + wv;
  int nw = gridDim.x * 4;
  int m = min(*cntF, NF_CAP);
  float bias = b1[lane];
  for (int r = wid; r < m; r += nw) {
    const float* a = aggx + (size_t)r * 128;
    float o = bias;
#pragma unroll
    for (int k = 0; k < 128; k += 4) {
      float4 av = *(const float4*)(a + k);   // wave-uniform broadcast
      o += av.x * Wl[(k + 0) * 64 + lane] + av.y * Wl[(k + 1) * 64 + lane] +
           av.z * Wl[(k + 2) * 64 + lane] + av.w * Wl[(k + 3) * 64 + lane];
    }
    h1[(size_t)r * 64 + lane] = o;
  }
}

// --- fused: aggregate h1 at 512 sel nodes, @W2 + b2, pairwise max, out -------
__global__ __launch_bounds__(128) void k_h2out(const float* __restrict__ h1,
    const int* __restrict__ sel, const int* __restrict__ fidx,
    const int* __restrict__ counts2, const int* __restrict__ fcols,
    const float* __restrict__ fvals, const float* __restrict__ dinv,
    const float* __restrict__ W2, const float* __restrict__ b2,
    float* __restrict__ out, int nb) {
  __shared__ float Wl[64 * 64];
  __shared__ float sag[2][64];
  __shared__ float hh[2][64];
  int t = threadIdx.x;
  for (int p = t; p < 64 * 16; p += 128)
    ((float4*)Wl)[p] = ((const float4*)W2)[p];
  __syncthreads();
  int lane = t & 63, wv = t >> 6;
  int b = blockIdx.x;
  if (b >= nb) return;
  int node = sel[2 * b + wv];
  int f = fidx[node];
  float dv = dinv[node];
  float acc = 0.f;
  int beg = f * STRIDE, end = beg + counts2[f];
  for (int p = beg; p < end; ++p) {
    int c = fcols[p];
    int g = fidx[c];                       // src of captured edge => in frontier
    acc += fvals[p] * dinv[c] * h1[(size_t)g * 64 + lane];
  }
  acc = dv * (acc + dv * h1[(size_t)f * 64 + lane]);
  sag[wv][lane] = acc;
  __syncthreads();
  float o = b2[lane];
#pragma unroll 8
  for (int k = 0; k < 64; ++k)
    o += sag[wv][k] * Wl[k * 64 + lane];
  hh[wv][lane] = o;
  __syncthreads();
  if (wv == 0)
    out[(size_t)b * 64 + lane] = fmaxf(hh[0][lane], hh[1][lane]);
}

extern "C" void kernel_launch(void* const* d_in, const int* in_sizes, int n_in,
                              void* d_out, int out_size, void* d_ws, size_t ws_size,
                              hipStream_t stream) {
  const float* x     = (const float*)d_in[0];
  const int*   ei    = (const int*)d_in[1];
  const float* ew    = (const float*)d_in[2];
  const int*   batch = (const int*)d_in[3];
  const float* W1    = (const float*)d_in[4];
  const float* b1    = (const float*)d_in[5];
  const float* W2    = (const float*)d_in[6];
  const float* b2    = (const float*)d_in[7];

  const int E  = in_sizes[2];
  const int N  = in_sizes[3];
  const int B  = out_size / 64;
  const int NC = N / 2;
  const int* srcI = ei;
  const int* dstI = ei + E;

  const int NBKT = (N + 255) >> 8;                  // 391 for N=100k
  const int CAP  = ((E + NBKT - 1) / NBKT) * 2;     // ~2x expected bucket load

  char* p = (char*)d_ws;
  auto alloc = [&](size_t bytes) -> char* {
    char* r = p;
    p += (bytes + 255) & ~size_t(255);
    return r;
  };
  float* dinv    = (float*)alloc((size_t)N * 4);
  unsigned int* mark1w = (unsigned int*)alloc((size_t)MAXW * 4);
  unsigned char* mark2 = (unsigned char*)alloc(N);
  int*   fidx    = (int*)alloc((size_t)N * 4);
  int*   list    = (int*)alloc((size_t)NF_CAP * 4);
  int*   counts2 = (int*)alloc((size_t)NF_CAP * 4);
  int*   first   = (int*)alloc((size_t)B * 4);
  int*   sel     = (int*)alloc((size_t)2 * B * 4);
  int*   cnt     = (int*)alloc(256);                // [0]=cntF
  int*   gcur    = (int*)alloc(NB512 * 4);
  uint2* bktbuf  = (uint2*)alloc((size_t)NBKT * CAP * 8);
  int*   fcols   = (int*)alloc((size_t)NF_CAP * STRIDE * 4);
  float* fvals   = (float*)alloc((size_t)NF_CAP * STRIDE * 4);
  float* aggx    = (float*)alloc((size_t)NF_CAP * 128 * 4);
  float* h1      = (float*)alloc((size_t)NF_CAP * 64 * 4);

  int gN = (N + 255) / 256;
  int gB = (E + CHUNK - 1) / CHUNK;
  int* cntF = cnt;

  k_init<<<gN, 256, 0, stream>>>(mark1w, mark2, fidx, first, cnt, gcur, N, B);
  k_first<<<(NC + 255) / 256, 256, 0, stream>>>(batch, first, NC);
  k_sel<<<(2 * B + 255) / 256, 256, 0, stream>>>(first, sel, mark1w, mark2, B, NC);
  k_bkt<<<gB, 256, 0, stream>>>(srcI, dstI, ew, mark1w, mark2, gcur, bktbuf, CAP, E);
  k_compact<<<gN, 256, 0, stream>>>(mark2, list, fidx, cntF, N);
  k_degscat<<<NBKT, 256, 0, stream>>>(gcur, bktbuf, CAP, fidx, dinv, counts2,
                                      fcols, fvals, N);
  k_agg<<<2048, 256, 0, stream>>>(x, list, cntF, counts2, fcols, fvals, dinv, aggx);
  k_gemm1<<<1024, 256, 0, stream>>>(aggx, cntF, W1, b1, h1);
  k_h2out<<<B, 128, 0, stream>>>(h1, sel, fidx, counts2, fcols, fvals, dinv, W2, b2,
                                 (float*)d_out, B);
}

// Round 10
// 142.619 us; speedup vs baseline: 1.2067x; 1.0888x over previous
//
#include <hip/hip_runtime.h>
#include <climits>

// ---------------------------------------------------------------------------
// GCN 2-layer + graclus pooling, frontier-restricted (~8.7k nodes).
//   k_bkt    : full-E pass; bucket edges by dst>>10 (98 buckets) via DIRECT
//              global scatter (register-held edges, LDS count+reserve only,
//              38k device atomics total, no staging/scan/dump phases).
//   k_degscat: per-bucket (1024 nodes) LDS degree -> dinv, plus capture of
//              edges whose dst is in the frontier into a fixed-stride CSR.
//   k_agg    : per-frontier-row gather of x rows (dinv[src] applied here).
//   k_gemm1  : h1 = aggx @ W1 + b1 (LDS-staged W).
//   k_h2out  : aggregate h1 at 512 sel nodes, @W2+b2, pairwise max -> out.
// No per-edge device atomics anywhere.
// ---------------------------------------------------------------------------

#define NF_CAP 40960
#define CHUNK 4096         // edges per k_bkt block (512 thr x 8)
#define STRIDE 128         // max in-degree bound (Poisson(16) -> P(>128)~0)
#define NBMAX 128          // padded bucket count (>= NBKT=98)
#define MAXW 3200          // mark1 bitset words for N<=102400

__global__ void k_init(unsigned int* mark1w, unsigned char* mark2,
                       int* fidx, int* first, int* cnt, int* gcur,
                       int n, int nb) {
  int i = blockIdx.x * blockDim.x + threadIdx.x;
  if (i < n) { mark2[i] = 0; fidx[i] = -1; }
  if (i < MAXW) mark1w[i] = 0;
  if (i < nb) first[i] = INT_MAX;
  if (i < 4) cnt[i] = 0;
  if (i < NBMAX) gcur[i] = 0;
}

// batch is sorted => bp[c]=batch[2c] is non-decreasing; first[b] = boundary c.
__global__ void k_first(const int* __restrict__ batch, int* first, int nc) {
  int c = blockIdx.x * blockDim.x + threadIdx.x;
  if (c >= nc) return;
  int b = batch[2 * c];
  if (c == 0 || batch[2 * c - 2] != b) first[b] = c;
}

__global__ void k_sel(const int* __restrict__ first, int* sel,
                      unsigned int* mark1w, unsigned char* mark2, int nb, int nc) {
  int t = blockIdx.x * blockDim.x + threadIdx.x;
  if (t >= 2 * nb) return;
  int f = first[t >> 1];
  f = min(f, nc - 1);            // JAX gather clamps (empty-graph case)
  int node = 2 * f + (t & 1);
  sel[t] = node;
  atomicOr(&mark1w[node >> 5], 1u << (node & 31));
  mark2[node] = 1;
}

// --- pass 1: bucket edges by dst>>10; direct global scatter ------------------
__global__ __launch_bounds__(512) void k_bkt(const int* __restrict__ src,
    const int* __restrict__ dst, const float* __restrict__ w,
    const unsigned int* __restrict__ mark1w, unsigned char* mark2,
    int* gcur, uint2* bktbuf, int cap, int e) {
  __shared__ int scnt[NBMAX], sgb[NBMAX];
  int t = threadIdx.x;
  if (t < NBMAX) scnt[t] = 0;
  __syncthreads();
  int i0 = blockIdx.x * CHUNK;
  int rd[8], rs[8];
  float rw[8];
#pragma unroll
  for (int k = 0; k < 8; ++k) {
    int i = i0 + t + k * 512;
    if (i < e) {
      int d = dst[i];
      int s = src[i];
      rd[k] = d; rs[k] = s; rw[k] = w[i];
      atomicAdd(&scnt[d >> 10], 1);
      if ((mark1w[d >> 5] >> (d & 31)) & 1u) mark2[s] = 1;  // L1-resident test
    } else {
      rd[k] = -1;
    }
  }
  __syncthreads();
  if (t < NBMAX) {
    int c = scnt[t];
    sgb[t] = c ? atomicAdd(&gcur[t], c) : 0;   // <=98 device atomics / block
    scnt[t] = 0;                               // same-thread reset: no race
  }
  __syncthreads();
#pragma unroll
  for (int k = 0; k < 8; ++k) {
    if (rd[k] >= 0) {
      int b = rd[k] >> 10;
      int pos = sgb[b] + atomicAdd(&scnt[b], 1);
      if (pos < cap)                            // contiguous per-block range:
        bktbuf[(size_t)b * cap + pos] =         // L2 write-combines the 8B stores
            make_uint2(((unsigned int)rs[k] << 10) | (unsigned int)(rd[k] & 1023),
                       __float_as_uint(rw[k]));
    }
  }
}

__global__ void k_compact(const unsigned char* __restrict__ mark2, int* list,
                          int* fidx, int* cntF, int n) {
  int i = blockIdx.x * blockDim.x + threadIdx.x;
  if (i < n && mark2[i]) {
    int p = atomicAdd(cntF, 1);
    if (p < NF_CAP) { list[p] = i; fidx[i] = p; }
  }
}

// --- pass 2: per-bucket degree -> dinv  +  frontier-edge capture (fused) -----
__global__ __launch_bounds__(1024) void k_degscat(const int* __restrict__ gcur,
    const uint2* __restrict__ bktbuf, int cap, const int* __restrict__ fidx,
    float* dinv, int* counts2, int* fcols, float* fvals, int n) {
  __shared__ float acc[1024];
  __shared__ int sfidx[1024];
  __shared__ int lcur[1024];
  int t = threadIdx.x, b = blockIdx.x;
  int gbase = b << 10;
  acc[t] = 0.f;
  int f0 = (gbase + t < n) ? fidx[gbase + t] : -1;
  sfidx[t] = f0;
  lcur[t] = (f0 >= 0) ? f0 * STRIDE : 0;
  __syncthreads();
  int m = min(gcur[b], cap);
  const uint2* base = bktbuf + (size_t)b * cap;
  for (int j = t; j < m; j += 1024) {
    uint2 u = base[j];
    int dl = (int)(u.x & 1023u);
    float wv = __uint_as_float(u.y);
    atomicAdd(&acc[dl], wv);                      // LDS fp32 atomic
    int f = sfidx[dl];
    if (f >= 0) {
      int pos = atomicAdd(&lcur[dl], 1);          // LDS cursor
      if (pos < (f + 1) * STRIDE) {               // fixed-stride CSR slot
        fcols[pos] = (int)(u.x >> 10);
        fvals[pos] = wv;                          // RAW w; dinv applied later
      }
    }
  }
  __syncthreads();
  int i = gbase + t;
  if (i < n) {
    dinv[i] = rsqrtf(1.0f + acc[t]);              // +1 = self-loop
    int f = sfidx[t];
    if (f >= 0) counts2[f] = min(lcur[t] - f * STRIDE, STRIDE);
  }
}

// --- aggregation of raw x at frontier rows: LDS-free, 4x unrolled gathers ----
__global__ __launch_bounds__(256) void k_agg(const float* __restrict__ x,
    const int* __restrict__ list, const int* __restrict__ cntF,
    const int* __restrict__ counts2, const int* __restrict__ fcols,
    const float* __restrict__ fvals, const float* __restrict__ dinv,
    float* __restrict__ aggx) {
  int lane = threadIdx.x & 63;
  int wid = (blockIdx.x * blockDim.x + threadIdx.x) >> 6;
  int nw = (gridDim.x * blockDim.x) >> 6;
  int m = min(*cntF, NF_CAP);
  const float2* x2 = (const float2*)x;
  float2* a2 = (float2*)aggx;
  for (int li = wid; li < m; li += nw) {
    int i = list[li];
    float dv = dinv[i];
    float2 xi = x2[(size_t)i * 64 + lane];
    float ax = 0.f, ay = 0.f;
    int beg = li * STRIDE;
    int end = beg + counts2[li];
    int p = beg;
    for (; p + 4 <= end; p += 4) {
      int c0 = fcols[p], c1 = fcols[p + 1], c2 = fcols[p + 2], c3 = fcols[p + 3];
      float v0 = fvals[p] * dinv[c0];             // dinv broadcast-loads ride
      float v1 = fvals[p + 1] * dinv[c1];         // alongside the row gathers
      float v2 = fvals[p + 2] * dinv[c2];
      float v3 = fvals[p + 3] * dinv[c3];
      float2 g0 = x2[(size_t)c0 * 64 + lane];
      float2 g1 = x2[(size_t)c1 * 64 + lane];
      float2 g2 = x2[(size_t)c2 * 64 + lane];
      float2 g3 = x2[(size_t)c3 * 64 + lane];
      ax += v0 * g0.x + v1 * g1.x + v2 * g2.x + v3 * g3.x;
      ay += v0 * g0.y + v1 * g1.y + v2 * g2.y + v3 * g3.y;
    }
    for (; p < end; ++p) {
      int c = fcols[p];
      float v = fvals[p] * dinv[c];
      float2 g = x2[(size_t)c * 64 + lane];
      ax += v * g.x;
      ay += v * g.y;
    }
    float2 r;
    r.x = dv * (ax + dv * xi.x);
    r.y = dv * (ay + dv * xi.y);
    a2[(size_t)li * 64 + lane] = r;
  }
}

// --- tiny GEMM over compact rows: h1 = aggx @ W1 + b1 ------------------------
__global__ __launch_bounds__(256) void k_gemm1(const float* __restrict__ aggx,
    const int* __restrict__ cntF, const float* __restrict__ W1,
    const float* __restrict__ b1, float* __restrict__ h1) {
  __shared__ float Wl[128 * 64];           // 32 KB
  int t = threadIdx.x;
  for (int p = t; p < 128 * 16; p += 256)
    ((float4*)Wl)[p] = ((const float4*)W1)[p];
  __syncthreads();
  int lane = t & 63, wv = t >> 6;
  int wid = blockIdx.x * 4 + wv;
  int nw = gridDim.x * 4;
  int m = min(*cntF, NF_CAP);
  float bias = b1[lane];
  for (int r = wid; r < m; r += nw) {
    const float* a = aggx + (size_t)r * 128;
    float o = bias;
#pragma unroll
    for (int k = 0; k < 128; k += 4) {
      float4 av = *(const float4*)(a + k);   // wave-uniform broadcast
      o += av.x * Wl[(k + 0) * 64 + lane] + av.y * Wl[(k + 1) * 64 + lane] +
           av.z * Wl[(k + 2) * 64 + lane] + av.w * Wl[(k + 3) * 64 + lane];
    }
    h1[(size_t)r * 64 + lane] = o;
  }
}

// --- fused: aggregate h1 at 512 sel nodes, @W2 + b2, pairwise max, out -------
__global__ __launch_bounds__(128) void k_h2out(const float* __restrict__ h1,
    const int* __restrict__ sel, const int* __restrict__ fidx,
    const int* __restrict__ counts2, const int* __restrict__ fcols,
    const float* __restrict__ fvals, const float* __restrict__ dinv,
    const float* __restrict__ W2, const float* __restrict__ b2,
    float* __restrict__ out, int nb) {
  __shared__ float Wl[64 * 64];
  __shared__ float sag[2][64];
  __shared__ float hh[2][64];
  int t = threadIdx.x;
  for (int p = t; p < 64 * 16; p += 128)
    ((float4*)Wl)[p] = ((const float4*)W2)[p];
  __syncthreads();
  int lane = t & 63, wv = t >> 6;
  int b = blockIdx.x;
  if (b >= nb) return;
  int node = sel[2 * b + wv];
  int f = fidx[node];
  float dv = dinv[node];
  float acc = 0.f;
  int beg = f * STRIDE, end = beg + counts2[f];
  for (int p = beg; p < end; ++p) {
    int c = fcols[p];
    int g = fidx[c];                       // src of captured edge => in frontier
    acc += fvals[p] * dinv[c] * h1[(size_t)g * 64 + lane];
  }
  acc = dv * (acc + dv * h1[(size_t)f * 64 + lane]);
  sag[wv][lane] = acc;
  __syncthreads();
  float o = b2[lane];
#pragma unroll 8
  for (int k = 0; k < 64; ++k)
    o += sag[wv][k] * Wl[k * 64 + lane];
  hh[wv][lane] = o;
  __syncthreads();
  if (wv == 0)
    out[(size_t)b * 64 + lane] = fmaxf(hh[0][lane], hh[1][lane]);
}

extern "C" void kernel_launch(void* const* d_in, const int* in_sizes, int n_in,
                              void* d_out, int out_size, void* d_ws, size_t ws_size,
                              hipStream_t stream) {
  const float* x     = (const float*)d_in[0];
  const int*   ei    = (const int*)d_in[1];
  const float* ew    = (const float*)d_in[2];
  const int*   batch = (const int*)d_in[3];
  const float* W1    = (const float*)d_in[4];
  const float* b1    = (const float*)d_in[5];
  const float* W2    = (const float*)d_in[6];
  const float* b2    = (const float*)d_in[7];

  const int E  = in_sizes[2];
  const int N  = in_sizes[3];
  const int B  = out_size / 64;
  const int NC = N / 2;
  const int* srcI = ei;
  const int* dstI = ei + E;

  const int NBKT = (N + 1023) >> 10;                // 98 for N=100k
  const int CAP  = ((E + NBKT - 1) / NBKT) * 2;     // ~2x expected bucket load

  char* p = (char*)d_ws;
  auto alloc = [&](size_t bytes) -> char* {
    char* r = p;
    p += (bytes + 255) & ~size_t(255);
    return r;
  };
  float* dinv    = (float*)alloc((size_t)N * 4);
  unsigned int* mark1w = (unsigned int*)alloc((size_t)MAXW * 4);
  unsigned char* mark2 = (unsigned char*)alloc(N);
  int*   fidx    = (int*)alloc((size_t)N * 4);
  int*   list    = (int*)alloc((size_t)NF_CAP * 4);
  int*   counts2 = (int*)alloc((size_t)NF_CAP * 4);
  int*   first   = (int*)alloc((size_t)B * 4);
  int*   sel     = (int*)alloc((size_t)2 * B * 4);
  int*   cnt     = (int*)alloc(256);                // [0]=cntF
  int*   gcur    = (int*)alloc(NBMAX * 4);
  uint2* bktbuf  = (uint2*)alloc((size_t)NBKT * CAP * 8);
  int*   fcols   = (int*)alloc((size_t)NF_CAP * STRIDE * 4);
  float* fvals   = (float*)alloc((size_t)NF_CAP * STRIDE * 4);
  float* aggx    = (float*)alloc((size_t)NF_CAP * 128 * 4);
  float* h1      = (float*)alloc((size_t)NF_CAP * 64 * 4);

  int gN = (N + 255) / 256;
  int gB = (E + CHUNK - 1) / CHUNK;
  int* cntF = cnt;

  k_init<<<gN, 256, 0, stream>>>(mark1w, mark2, fidx, first, cnt, gcur, N, B);
  k_first<<<(NC + 255) / 256, 256, 0, stream>>>(batch, first, NC);
  k_sel<<<(2 * B + 255) / 256, 256, 0, stream>>>(first, sel, mark1w, mark2, B, NC);
  k_bkt<<<gB, 512, 0, stream>>>(srcI, dstI, ew, mark1w, mark2, gcur, bktbuf, CAP, E);
  k_compact<<<gN, 256, 0, stream>>>(mark2, list, fidx, cntF, N);
  k_degscat<<<NBKT, 1024, 0, stream>>>(gcur, bktbuf, CAP, fidx, dinv, counts2,
                                       fcols, fvals, N);
  k_agg<<<2048, 256, 0, stream>>>(x, list, cntF, counts2, fcols, fvals, dinv, aggx);
  k_gemm1<<<1024, 256, 0, stream>>>(aggx, cntF, W1, b1, h1);
  k_h2out<<<B, 128, 0, stream>>>(h1, sel, fidx, counts2, fcols, fvals, dinv, W2, b2,
                                 (float*)d_out, B);
}

// Round 11
// 123.694 us; speedup vs baseline: 1.3913x; 1.1530x over previous
//
#include <hip/hip_runtime.h>
#include <climits>

// ---------------------------------------------------------------------------
// GCN 2-layer + graclus pooling, frontier-restricted (~8.7k nodes).
// Algebra: h2 = (A^2 x)(W1 W2) + (A 1)(b1 W2) + b2  -> no per-node h1 needed.
//   k_init   : elementwise init; blocks 0-2 also compute WW=W1@W2, bW=b1@W2.
//   k_first  : boundary-detect first cluster per graph (batch sorted).
//   k_sel    : selected nodes -> sel[], mark1 bitset, mark2.
//   k_bkt    : full-E pass; bucket edges by dst>>10 via direct global scatter
//              (register-held edges, LDS count+reserve, 38k device atomics).
//   k_degscat: per-bucket: local compact (1 dev atomic/block) -> fidx/list,
//              LDS degree -> dinv, frontier-edge capture -> fixed-stride CSR.
//   k_agg    : per-frontier-row gather of x rows -> aggx (A x at frontier).
//   k_h2out  : aggregate aggx at 512 sel nodes (A^2 x), @WW + s*bW + b2,
//              pairwise max -> out.
// No per-edge device atomics anywhere.
// ---------------------------------------------------------------------------

#define NF_CAP 40960
#define CHUNK 4096         // edges per k_bkt block (512 thr x 8)
#define STRIDE 128         // max in-degree bound (Poisson(16) -> P(>128)~0)
#define NBMAX 128          // padded bucket count (>= NBKT=98)
#define MAXW 3200          // mark1 bitset words for N<=102400

__global__ void k_init(unsigned int* mark1w, unsigned char* mark2,
                       int* first, int* cnt, int* gcur,
                       float* WW, float* bW,
                       const float* __restrict__ W1, const float* __restrict__ W2,
                       const float* __restrict__ b1, int n, int nb) {
  int i = blockIdx.x * blockDim.x + threadIdx.x;
  if (i < n) mark2[i] = 0;
  if (i < MAXW) mark1w[i] = 0;
  if (i < nb) first[i] = INT_MAX;
  if (i < 4) cnt[i] = 0;
  if (i < NBMAX) gcur[i] = 0;
  // blocks 0,1: WW = W1(128x64) @ W2(64x64); block 2: bW = b1 @ W2
  int t = threadIdx.x;
  int lane = t & 63, wv = t >> 6;
  if (blockIdx.x < 2) {
    int k0 = blockIdx.x * 64 + wv * 16;
#pragma unroll 1
    for (int k = k0; k < k0 + 16; ++k) {
      float acc = 0.f;
#pragma unroll 8
      for (int m = 0; m < 64; ++m)
        acc += W1[k * 64 + m] * W2[m * 64 + lane];
      WW[k * 64 + lane] = acc;
    }
  } else if (blockIdx.x == 2 && wv == 0) {
    float acc = 0.f;
#pragma unroll 8
    for (int m = 0; m < 64; ++m)
      acc += b1[m] * W2[m * 64 + lane];
    bW[lane] = acc;
  }
}

// batch is sorted => bp[c]=batch[2c] is non-decreasing; first[b] = boundary c.
__global__ void k_first(const int* __restrict__ batch, int* first, int nc) {
  int c = blockIdx.x * blockDim.x + threadIdx.x;
  if (c >= nc) return;
  int b = batch[2 * c];
  if (c == 0 || batch[2 * c - 2] != b) first[b] = c;
}

__global__ void k_sel(const int* __restrict__ first, int* sel,
                      unsigned int* mark1w, unsigned char* mark2, int nb, int nc) {
  int t = blockIdx.x * blockDim.x + threadIdx.x;
  if (t >= 2 * nb) return;
  int f = first[t >> 1];
  f = min(f, nc - 1);            // JAX gather clamps (empty-graph case)
  int node = 2 * f + (t & 1);
  sel[t] = node;
  atomicOr(&mark1w[node >> 5], 1u << (node & 31));
  mark2[node] = 1;
}

// --- pass 1: bucket edges by dst>>10; direct global scatter ------------------
__global__ __launch_bounds__(512) void k_bkt(const int* __restrict__ src,
    const int* __restrict__ dst, const float* __restrict__ w,
    const unsigned int* __restrict__ mark1w, unsigned char* mark2,
    int* gcur, uint2* bktbuf, int cap, int e) {
  __shared__ int scnt[NBMAX], sgb[NBMAX];
  int t = threadIdx.x;
  if (t < NBMAX) scnt[t] = 0;
  __syncthreads();
  int i0 = blockIdx.x * CHUNK;
  int rd[8], rs[8];
  float rw[8];
#pragma unroll
  for (int k = 0; k < 8; ++k) {
    int i = i0 + t + k * 512;
    if (i < e) {
      int d = dst[i];
      int s = src[i];
      rd[k] = d; rs[k] = s; rw[k] = w[i];
      atomicAdd(&scnt[d >> 10], 1);
      if ((mark1w[d >> 5] >> (d & 31)) & 1u) mark2[s] = 1;  // L1-resident test
    } else {
      rd[k] = -1;
    }
  }
  __syncthreads();
  if (t < NBMAX) {
    int c = scnt[t];
    sgb[t] = c ? atomicAdd(&gcur[t], c) : 0;   // <=98 device atomics / block
    scnt[t] = 0;                               // same-thread reset: no race
  }
  __syncthreads();
#pragma unroll
  for (int k = 0; k < 8; ++k) {
    if (rd[k] >= 0) {
      int b = rd[k] >> 10;
      int pos = sgb[b] + atomicAdd(&scnt[b], 1);
      if (pos < cap)                            // contiguous per-block range:
        bktbuf[(size_t)b * cap + pos] =         // L2 write-combines the 8B stores
            make_uint2(((unsigned int)rs[k] << 10) | (unsigned int)(rd[k] & 1023),
                       __float_as_uint(rw[k]));
    }
  }
}

// --- pass 2: per-bucket compact + degree -> dinv + frontier-edge capture -----
__global__ __launch_bounds__(1024) void k_degscat(const int* __restrict__ gcur,
    const uint2* __restrict__ bktbuf, int cap, const unsigned char* __restrict__ mark2,
    int* cntF, int* fidx, int* list,
    float* dinv, int* counts2, int* fcols, float* fvals, int n) {
  __shared__ float acc[1024];
  __shared__ int sfidx[1024];
  __shared__ int lcur[1024];
  __shared__ int sd[1024];
  __shared__ int base_s;
  int t = threadIdx.x, b = blockIdx.x;
  int gbase = b << 10;
  int i = gbase + t;
  acc[t] = 0.f;
  // local compact: prefix scan of mark2 flags, one device atomic per block
  int flag = (i < n && mark2[i]) ? 1 : 0;
  sd[t] = flag;
  __syncthreads();
  for (int off = 1; off < 1024; off <<= 1) {
    int a = (t >= off) ? sd[t - off] : 0;
    __syncthreads();
    sd[t] += a;
    __syncthreads();
  }
  int incl = sd[t];
  if (t == 1023) base_s = atomicAdd(cntF, incl);   // incl@1023 == block total
  __syncthreads();
  int f0 = -1;
  if (flag) {
    int g = base_s + incl - 1;
    if (g < NF_CAP) { f0 = g; fidx[i] = g; list[g] = i; }
  }
  sfidx[t] = f0;
  lcur[t] = (f0 >= 0) ? f0 * STRIDE : 0;
  __syncthreads();
  int m = min(gcur[b], cap);
  const uint2* base = bktbuf + (size_t)b * cap;
  for (int j = t; j < m; j += 1024) {
    uint2 u = base[j];
    int dl = (int)(u.x & 1023u);
    float wv = __uint_as_float(u.y);
    atomicAdd(&acc[dl], wv);                      // LDS fp32 atomic
    int f = sfidx[dl];
    if (f >= 0) {
      int pos = atomicAdd(&lcur[dl], 1);          // LDS cursor
      if (pos < (f + 1) * STRIDE) {               // fixed-stride CSR slot
        fcols[pos] = (int)(u.x >> 10);
        fvals[pos] = wv;                          // RAW w; dinv applied later
      }
    }
  }
  __syncthreads();
  if (i < n) {
    dinv[i] = rsqrtf(1.0f + acc[t]);              // +1 = self-loop
    int f = sfidx[t];
    if (f >= 0) counts2[f] = min(lcur[t] - f * STRIDE, STRIDE);
  }
}

// --- aggregation of raw x at frontier rows: LDS-free, 4x unrolled gathers ----
__global__ __launch_bounds__(256) void k_agg(const float* __restrict__ x,
    const int* __restrict__ list, const int* __restrict__ cntF,
    const int* __restrict__ counts2, const int* __restrict__ fcols,
    const float* __restrict__ fvals, const float* __restrict__ dinv,
    float* __restrict__ aggx) {
  int lane = threadIdx.x & 63;
  int wid = (blockIdx.x * blockDim.x + threadIdx.x) >> 6;
  int nw = (gridDim.x * blockDim.x) >> 6;
  int m = min(*cntF, NF_CAP);
  const float2* x2 = (const float2*)x;
  float2* a2 = (float2*)aggx;
  for (int li = wid; li < m; li += nw) {
    int i = list[li];
    float dv = dinv[i];
    float2 xi = x2[(size_t)i * 64 + lane];
    float ax = 0.f, ay = 0.f;
    int beg = li * STRIDE;
    int end = beg + counts2[li];
    int p = beg;
    for (; p + 4 <= end; p += 4) {
      int c0 = fcols[p], c1 = fcols[p + 1], c2 = fcols[p + 2], c3 = fcols[p + 3];
      float v0 = fvals[p] * dinv[c0];             // dinv broadcast-loads ride
      float v1 = fvals[p + 1] * dinv[c1];         // alongside the row gathers
      float v2 = fvals[p + 2] * dinv[c2];
      float v3 = fvals[p + 3] * dinv[c3];
      float2 g0 = x2[(size_t)c0 * 64 + lane];
      float2 g1 = x2[(size_t)c1 * 64 + lane];
      float2 g2 = x2[(size_t)c2 * 64 + lane];
      float2 g3 = x2[(size_t)c3 * 64 + lane];
      ax += v0 * g0.x + v1 * g1.x + v2 * g2.x + v3 * g3.x;
      ay += v0 * g0.y + v1 * g1.y + v2 * g2.y + v3 * g3.y;
    }
    for (; p < end; ++p) {
      int c = fcols[p];
      float v = fvals[p] * dinv[c];
      float2 g = x2[(size_t)c * 64 + lane];
      ax += v * g.x;
      ay += v * g.y;
    }
    float2 r;
    r.x = dv * (ax + dv * xi.x);
    r.y = dv * (ay + dv * xi.y);
    a2[(size_t)li * 64 + lane] = r;
  }
}

// --- fused: aggregate aggx at 512 sel nodes, @WW + s*bW + b2, max, out -------
__global__ __launch_bounds__(128) void k_h2out(const float* __restrict__ aggx,
    const int* __restrict__ sel, const int* __restrict__ fidx,
    const int* __restrict__ counts2, const int* __restrict__ fcols,
    const float* __restrict__ fvals, const float* __restrict__ dinv,
    const float* __restrict__ WW, const float* __restrict__ bW,
    const float* __restrict__ b2, float* __restrict__ out, int nb) {
  __shared__ float Wl[128 * 64];           // 32 KB
  __shared__ float sag[2][128];
  __shared__ float hh[2][64];
  int t = threadIdx.x;
  for (int p = t; p < 128 * 16; p += 128)
    ((float4*)Wl)[p] = ((const float4*)WW)[p];
  __syncthreads();
  int lane = t & 63, wv = t >> 6;
  int b = blockIdx.x;
  if (b >= nb) return;
  int node = sel[2 * b + wv];
  int f = fidx[node];
  float dv = dinv[node];
  const float2* a2 = (const float2*)aggx;
  float2 acc = {0.f, 0.f};
  float sv = 0.f;                          // rowsum (same in all lanes)
  int beg = f * STRIDE, end = beg + counts2[f];
  for (int p = beg; p < end; ++p) {
    int c = fcols[p];
    float v = fvals[p] * dinv[c];
    int g = fidx[c];                       // src in frontier (dst was selected)
    float2 r = a2[(size_t)g * 64 + lane];
    acc.x += v * r.x;
    acc.y += v * r.y;
    sv += v;
  }
  float2 rs = a2[(size_t)f * 64 + lane];
  acc.x = dv * (acc.x + dv * rs.x);
  acc.y = dv * (acc.y + dv * rs.y);
  float sfin = dv * (sv + dv);             // (A 1)[node]
  sag[wv][2 * lane] = acc.x;
  sag[wv][2 * lane + 1] = acc.y;
  __syncthreads();
  float o = b2[lane] + sfin * bW[lane];
#pragma unroll 8
  for (int k = 0; k < 128; ++k)
    o += sag[wv][k] * Wl[k * 64 + lane];
  hh[wv][lane] = o;
  __syncthreads();
  if (wv == 0)
    out[(size_t)b * 64 + lane] = fmaxf(hh[0][lane], hh[1][lane]);
}

extern "C" void kernel_launch(void* const* d_in, const int* in_sizes, int n_in,
                              void* d_out, int out_size, void* d_ws, size_t ws_size,
                              hipStream_t stream) {
  const float* x     = (const float*)d_in[0];
  const int*   ei    = (const int*)d_in[1];
  const float* ew    = (const float*)d_in[2];
  const int*   batch = (const int*)d_in[3];
  const float* W1    = (const float*)d_in[4];
  const float* b1    = (const float*)d_in[5];
  const float* W2    = (const float*)d_in[6];
  const float* b2    = (const float*)d_in[7];

  const int E  = in_sizes[2];
  const int N  = in_sizes[3];
  const int B  = out_size / 64;
  const int NC = N / 2;
  const int* srcI = ei;
  const int* dstI = ei + E;

  const int NBKT = (N + 1023) >> 10;                // 98 for N=100k
  const int CAP  = ((E + NBKT - 1) / NBKT) * 2;     // ~2x expected bucket load

  char* p = (char*)d_ws;
  auto alloc = [&](size_t bytes) -> char* {
    char* r = p;
    p += (bytes + 255) & ~size_t(255);
    return r;
  };
  float* dinv    = (float*)alloc((size_t)N * 4);
  unsigned int* mark1w = (unsigned int*)alloc((size_t)MAXW * 4);
  unsigned char* mark2 = (unsigned char*)alloc(N);
  int*   fidx    = (int*)alloc((size_t)N * 4);
  int*   list    = (int*)alloc((size_t)NF_CAP * 4);
  int*   counts2 = (int*)alloc((size_t)NF_CAP * 4);
  int*   first   = (int*)alloc((size_t)B * 4);
  int*   sel     = (int*)alloc((size_t)2 * B * 4);
  int*   cnt     = (int*)alloc(256);                // [0]=cntF
  int*   gcur    = (int*)alloc(NBMAX * 4);
  float* WW      = (float*)alloc(128 * 64 * 4);
  float* bW      = (float*)alloc(64 * 4);
  uint2* bktbuf  = (uint2*)alloc((size_t)NBKT * CAP * 8);
  int*   fcols   = (int*)alloc((size_t)NF_CAP * STRIDE * 4);
  float* fvals   = (float*)alloc((size_t)NF_CAP * STRIDE * 4);
  float* aggx    = (float*)alloc((size_t)NF_CAP * 128 * 4);

  int gN = (N + 255) / 256;
  int gB = (E + CHUNK - 1) / CHUNK;
  int* cntF = cnt;

  k_init<<<gN, 256, 0, stream>>>(mark1w, mark2, first, cnt, gcur, WW, bW,
                                 W1, W2, b1, N, B);
  k_first<<<(NC + 255) / 256, 256, 0, stream>>>(batch, first, NC);
  k_sel<<<(2 * B + 255) / 256, 256, 0, stream>>>(first, sel, mark1w, mark2, B, NC);
  k_bkt<<<gB, 512, 0, stream>>>(srcI, dstI, ew, mark1w, mark2, gcur, bktbuf, CAP, E);
  k_degscat<<<NBKT, 1024, 0, stream>>>(gcur, bktbuf, CAP, mark2, cntF, fidx, list,
                                       dinv, counts2, fcols, fvals, N);
  k_agg<<<2048, 256, 0, stream>>>(x, list, cntF, counts2, fcols, fvals, dinv, aggx);
  k_h2out<<<B, 128, 0, stream>>>(aggx, sel, fidx, counts2, fcols, fvals, dinv,
                                 WW, bW, b2, (float*)d_out, B);
}

// Round 12
// 122.648 us; speedup vs baseline: 1.4032x; 1.0085x over previous
//
#include <hip/hip_runtime.h>
#include <climits>

// ---------------------------------------------------------------------------
// GCN 2-layer + graclus pooling, frontier-restricted (~8.7k nodes).
// Algebra: h2 = (A^2 x)(W1 W2) + (A 1)(b1 W2) + b2  -> no per-node h1 needed.
//   k_init    : init + (blocks 0-2) WW=W1@W2, bW=b1@W2.
//   k_firstsel: single block; batch sorted -> boundary-detect first[] in LDS,
//               then sel[] + mark1 bitset + mark2.
//   k_bkt     : full-E pass; 256-node buckets (dst>>8), direct global scatter,
//               196 blocks x 8192 edges (halved atomic-reservation depth).
//   k_degscat : 391 blocks x 256 thr (full CU coverage): local compact ->
//               fidx/list, LDS degree -> dinv, frontier-edge capture -> CSR.
//   k_agg     : wave/row, float4 half-wave gathers (2 edges/iter, 8 in flight).
//   k_h2out   : same gather pattern at 512 sel nodes, @WW + s*bW + b2, max.
// No per-edge device atomics anywhere.
// ---------------------------------------------------------------------------

#define NF_CAP 40960
#define CHUNK 8192         // edges per k_bkt block (1024 thr x 8)
#define STRIDE 128         // max in-degree bound
#define BK_BITS 8          // 256-node buckets
#define NBMAX 512          // padded bucket count (>= NBKT=391)
#define MAXW 3200          // mark1 bitset words for N<=102400

__global__ void k_init(unsigned int* mark1w, unsigned char* mark2,
                       int* cnt, int* gcur, float* WW, float* bW,
                       const float* __restrict__ W1, const float* __restrict__ W2,
                       const float* __restrict__ b1, int n) {
  int i = blockIdx.x * blockDim.x + threadIdx.x;
  if (i < n) mark2[i] = 0;
  if (i < MAXW) mark1w[i] = 0;
  if (i < 4) cnt[i] = 0;
  if (i < NBMAX) gcur[i] = 0;
  int t = threadIdx.x;
  int lane = t & 63, wv = t >> 6;
  if (blockIdx.x < 2) {                       // WW = W1(128x64) @ W2(64x64)
    int k0 = blockIdx.x * 64 + wv * 16;
#pragma unroll 1
    for (int k = k0; k < k0 + 16; ++k) {
      float acc = 0.f;
#pragma unroll 8
      for (int m = 0; m < 64; ++m)
        acc += W1[k * 64 + m] * W2[m * 64 + lane];
      WW[k * 64 + lane] = acc;
    }
  } else if (blockIdx.x == 2 && wv == 0) {    // bW = b1 @ W2
    float acc = 0.f;
#pragma unroll 8
    for (int m = 0; m < 64; ++m)
      acc += b1[m] * W2[m * 64 + lane];
    bW[lane] = acc;
  }
}

// single block: batch sorted -> first boundaries in LDS, then selection+marks
__global__ __launch_bounds__(1024) void k_firstsel(const int* __restrict__ batch,
    int* sel, unsigned int* mark1w, unsigned char* mark2, int nb, int nc) {
  __shared__ int sfirst[512];
  int t = threadIdx.x;
  if (t < 512) sfirst[t] = INT_MAX;
  __syncthreads();
  for (int c = t; c < nc; c += 1024) {
    int b = batch[2 * c];
    if (c == 0 || batch[2 * c - 2] != b) sfirst[b] = c;   // <=1 boundary per b
  }
  __syncthreads();
  if (t < 2 * nb) {
    int f = min(sfirst[t >> 1], nc - 1);   // JAX gather clamp (empty graph)
    int node = 2 * f + (t & 1);
    sel[t] = node;
    atomicOr(&mark1w[node >> 5], 1u << (node & 31));
    mark2[node] = 1;
  }
}

// --- pass 1: bucket edges by dst>>8; direct global scatter -------------------
__global__ __launch_bounds__(1024) void k_bkt(const int* __restrict__ src,
    const int* __restrict__ dst, const float* __restrict__ w,
    const unsigned int* __restrict__ mark1w, unsigned char* mark2,
    int* gcur, uint2* bktbuf, int cap, int e) {
  __shared__ int scnt[NBMAX], sgb[NBMAX];
  int t = threadIdx.x;
  if (t < NBMAX) scnt[t] = 0;
  __syncthreads();
  int i0 = blockIdx.x * CHUNK;
  int rd[8], rs[8];
  float rw[8];
#pragma unroll
  for (int k = 0; k < 8; ++k) {
    int i = i0 + t + k * 1024;
    if (i < e) {
      int d = dst[i];
      int s = src[i];
      rd[k] = d; rs[k] = s; rw[k] = w[i];
      atomicAdd(&scnt[d >> BK_BITS], 1);
      if ((mark1w[d >> 5] >> (d & 31)) & 1u) mark2[s] = 1;  // L1-resident test
    } else {
      rd[k] = -1;
    }
  }
  __syncthreads();
  if (t < NBMAX) {
    int c = scnt[t];
    sgb[t] = c ? atomicAdd(&gcur[t], c) : 0;   // <=391 dev atomics / block
    scnt[t] = 0;                               // same-thread reset: no race
  }
  __syncthreads();
#pragma unroll
  for (int k = 0; k < 8; ++k) {
    if (rd[k] >= 0) {
      int b = rd[k] >> BK_BITS;
      int pos = sgb[b] + atomicAdd(&scnt[b], 1);
      if (pos < cap)
        bktbuf[(size_t)b * cap + pos] =
            make_uint2(((unsigned int)rs[k] << BK_BITS) | (unsigned int)(rd[k] & 255),
                       __float_as_uint(rw[k]));
    }
  }
}

// --- pass 2: per-bucket compact + degree -> dinv + frontier-edge capture -----
__global__ __launch_bounds__(256) void k_degscat(const int* __restrict__ gcur,
    const uint2* __restrict__ bktbuf, int cap, const unsigned char* __restrict__ mark2,
    int* cntF, int* fidx, int* list,
    float* dinv, int* counts2, int* fcols, float* fvals, int n) {
  __shared__ float acc[256];
  __shared__ int sfidx[256];
  __shared__ int lcur[256];
  __shared__ int sd[256];
  __shared__ int base_s;
  int t = threadIdx.x, b = blockIdx.x;
  int gbase = b << BK_BITS;
  int i = gbase + t;
  acc[t] = 0.f;
  // local compact: prefix scan of mark2 flags, one device atomic per block
  int flag = (i < n && mark2[i]) ? 1 : 0;
  sd[t] = flag;
  __syncthreads();
  for (int off = 1; off < 256; off <<= 1) {
    int a = (t >= off) ? sd[t - off] : 0;
    __syncthreads();
    sd[t] += a;
    __syncthreads();
  }
  int incl = sd[t];
  if (t == 255) base_s = atomicAdd(cntF, incl);
  __syncthreads();
  int f0 = -1;
  if (flag) {
    int g = base_s + incl - 1;
    if (g < NF_CAP) { f0 = g; fidx[i] = g; list[g] = i; }
  }
  sfidx[t] = f0;
  lcur[t] = (f0 >= 0) ? f0 * STRIDE : 0;
  __syncthreads();
  int m = min(gcur[b], cap);
  const uint2* base = bktbuf + (size_t)b * cap;
  for (int j = t; j < m; j += 256) {
    uint2 u = base[j];
    int dl = (int)(u.x & 255u);
    float wv = __uint_as_float(u.y);
    atomicAdd(&acc[dl], wv);                      // LDS fp32 atomic
    int f = sfidx[dl];
    if (f >= 0) {
      int pos = atomicAdd(&lcur[dl], 1);          // LDS cursor
      if (pos < (f + 1) * STRIDE) {
        fcols[pos] = (int)(u.x >> BK_BITS);
        fvals[pos] = wv;                          // RAW w; dinv applied later
      }
    }
  }
  __syncthreads();
  if (i < n) {
    dinv[i] = rsqrtf(1.0f + acc[t]);              // +1 = self-loop
    int f = sfidx[t];
    if (f >= 0) counts2[f] = min(lcur[t] - f * STRIDE, STRIDE);
  }
}

// --- aggregation at frontier rows: float4 half-wave gathers ------------------
__global__ __launch_bounds__(256) void k_agg(const float* __restrict__ x,
    const int* __restrict__ list, const int* __restrict__ cntF,
    const int* __restrict__ counts2, const int* __restrict__ fcols,
    const float* __restrict__ fvals, const float* __restrict__ dinv,
    float* __restrict__ aggx) {
  int lane = threadIdx.x & 63;
  int half = lane >> 5, sub = lane & 31;
  int wid = (blockIdx.x * blockDim.x + threadIdx.x) >> 6;
  int nw = (gridDim.x * blockDim.x) >> 6;
  int m = min(*cntF, NF_CAP);
  const float4* x4 = (const float4*)x;      // row i = x4[i*32 + sub]
  float4* a4 = (float4*)aggx;
  for (int li = wid; li < m; li += nw) {
    int i = list[li];
    float dv = dinv[i];
    float4 xi = x4[(size_t)i * 32 + sub];
    float ax = 0.f, ay = 0.f, az = 0.f, aw = 0.f;
    int beg = li * STRIDE;
    int end = beg + counts2[li];
    int p = beg;
    for (; p + 8 <= end; p += 8) {          // 8 edges: 4 gathers/lane in flight
      int cA = fcols[p + half],     cB = fcols[p + 2 + half];
      int cC = fcols[p + 4 + half], cD = fcols[p + 6 + half];
      float vA = fvals[p + half] * dinv[cA];
      float vB = fvals[p + 2 + half] * dinv[cB];
      float vC = fvals[p + 4 + half] * dinv[cC];
      float vD = fvals[p + 6 + half] * dinv[cD];
      float4 gA = x4[(size_t)cA * 32 + sub];
      float4 gB = x4[(size_t)cB * 32 + sub];
      float4 gC = x4[(size_t)cC * 32 + sub];
      float4 gD = x4[(size_t)cD * 32 + sub];
      ax += vA * gA.x + vB * gB.x + vC * gC.x + vD * gD.x;
      ay += vA * gA.y + vB * gB.y + vC * gC.y + vD * gD.y;
      az += vA * gA.z + vB * gB.z + vC * gC.z + vD * gD.z;
      aw += vA * gA.w + vB * gB.w + vC * gC.w + vD * gD.w;
    }
    for (; p + 2 <= end; p += 2) {          // 2 edges (one per half)
      int c = fcols[p + half];
      float v = fvals[p + half] * dinv[c];
      float4 g = x4[(size_t)c * 32 + sub];
      ax += v * g.x; ay += v * g.y; az += v * g.z; aw += v * g.w;
    }
    if (p < end && half == 0) {             // odd tail edge
      int c = fcols[p];
      float v = fvals[p] * dinv[c];
      float4 g = x4[(size_t)c * 32 + sub];
      ax += v * g.x; ay += v * g.y; az += v * g.z; aw += v * g.w;
    }
    ax += __shfl(ax, lane ^ 32);            // combine halves
    ay += __shfl(ay, lane ^ 32);
    az += __shfl(az, lane ^ 32);
    aw += __shfl(aw, lane ^ 32);
    if (half == 0) {
      float4 r;
      r.x = dv * (ax + dv * xi.x);
      r.y = dv * (ay + dv * xi.y);
      r.z = dv * (az + dv * xi.z);
      r.w = dv * (aw + dv * xi.w);
      a4[(size_t)li * 32 + sub] = r;
    }
  }
}

// --- fused: aggregate aggx at 512 sel nodes, @WW + s*bW + b2, max, out -------
__global__ __launch_bounds__(128) void k_h2out(const float* __restrict__ aggx,
    const int* __restrict__ sel, const int* __restrict__ fidx,
    const int* __restrict__ counts2, const int* __restrict__ fcols,
    const float* __restrict__ fvals, const float* __restrict__ dinv,
    const float* __restrict__ WW, const float* __restrict__ bW,
    const float* __restrict__ b2, float* __restrict__ out, int nb) {
  __shared__ float Wl[128 * 64];            // 32 KB
  __shared__ float sag[2][128];
  __shared__ float hh[2][64];
  int t = threadIdx.x;
  for (int p = t; p < 128 * 16; p += 128)
    ((float4*)Wl)[p] = ((const float4*)WW)[p];
  __syncthreads();
  int lane = t & 63, wv = t >> 6;
  int half = lane >> 5, sub = lane & 31;
  int b = blockIdx.x;
  if (b >= nb) return;
  int node = sel[2 * b + wv];
  int f = fidx[node];
  float dv = dinv[node];
  const float4* a4 = (const float4*)aggx;
  float ax = 0.f, ay = 0.f, az = 0.f, aw = 0.f, sv = 0.f;
  int beg = f * STRIDE, end = beg + counts2[f];
  int p = beg;
  for (; p + 2 <= end; p += 2) {
    int c = fcols[p + half];
    float v = fvals[p + half] * dinv[c];
    int g = fidx[c];                        // src in frontier (dst selected)
    float4 r = a4[(size_t)g * 32 + sub];
    ax += v * r.x; ay += v * r.y; az += v * r.z; aw += v * r.w;
    sv += v;
  }
  if (p < end && half == 0) {
    int c = fcols[p];
    float v = fvals[p] * dinv[c];
    int g = fidx[c];
    float4 r = a4[(size_t)g * 32 + sub];
    ax += v * r.x; ay += v * r.y; az += v * r.z; aw += v * r.w;
    sv += v;
  }
  ax += __shfl(ax, lane ^ 32);
  ay += __shfl(ay, lane ^ 32);
  az += __shfl(az, lane ^ 32);
  aw += __shfl(aw, lane ^ 32);
  sv += __shfl(sv, lane ^ 32);
  float4 rs = a4[(size_t)f * 32 + sub];
  if (half == 0) {
    sag[wv][4 * sub + 0] = dv * (ax + dv * rs.x);
    sag[wv][4 * sub + 1] = dv * (ay + dv * rs.y);
    sag[wv][4 * sub + 2] = dv * (az + dv * rs.z);
    sag[wv][4 * sub + 3] = dv * (aw + dv * rs.w);
  }
  float sfin = dv * (sv + dv);              // (A 1)[node]
  __syncthreads();
  float o = b2[lane] + sfin * bW[lane];
#pragma unroll 8
  for (int k = 0; k < 128; ++k)
    o += sag[wv][k] * Wl[k * 64 + lane];
  hh[wv][lane] = o;
  __syncthreads();
  if (wv == 0)
    out[(size_t)b * 64 + lane] = fmaxf(hh[0][lane], hh[1][lane]);
}

extern "C" void kernel_launch(void* const* d_in, const int* in_sizes, int n_in,
                              void* d_out, int out_size, void* d_ws, size_t ws_size,
                              hipStream_t stream) {
  const float* x     = (const float*)d_in[0];
  const int*   ei    = (const int*)d_in[1];
  const float* ew    = (const float*)d_in[2];
  const int*   batch = (const int*)d_in[3];
  const float* W1    = (const float*)d_in[4];
  const float* b1    = (const float*)d_in[5];
  const float* W2    = (const float*)d_in[6];
  const float* b2    = (const float*)d_in[7];

  const int E  = in_sizes[2];
  const int N  = in_sizes[3];
  const int B  = out_size / 64;
  const int NC = N / 2;
  const int* srcI = ei;
  const int* dstI = ei + E;

  const int NBKT = (N + 255) >> BK_BITS;            // 391 for N=100k
  const int CAP  = ((E + NBKT - 1) / NBKT) * 2;     // ~2x expected bucket load

  char* p = (char*)d_ws;
  auto alloc = [&](size_t bytes) -> char* {
    char* r = p;
    p += (bytes + 255) & ~size_t(255);
    return r;
  };
  float* dinv    = (float*)alloc((size_t)N * 4);
  unsigned int* mark1w = (unsigned int*)alloc((size_t)MAXW * 4);
  unsigned char* mark2 = (unsigned char*)alloc(N);
  int*   fidx    = (int*)alloc((size_t)N * 4);
  int*   list    = (int*)alloc((size_t)NF_CAP * 4);
  int*   counts2 = (int*)alloc((size_t)NF_CAP * 4);
  int*   sel     = (int*)alloc((size_t)2 * B * 4);
  int*   cnt     = (int*)alloc(256);                // [0]=cntF
  int*   gcur    = (int*)alloc(NBMAX * 4);
  float* WW      = (float*)alloc(128 * 64 * 4);
  float* bW      = (float*)alloc(64 * 4);
  uint2* bktbuf  = (uint2*)alloc((size_t)NBKT * CAP * 8);
  int*   fcols   = (int*)alloc((size_t)NF_CAP * STRIDE * 4);
  float* fvals   = (float*)alloc((size_t)NF_CAP * STRIDE * 4);
  float* aggx    = (float*)alloc((size_t)NF_CAP * 128 * 4);

  int gN = (N + 255) / 256;
  int gB = (E + CHUNK - 1) / CHUNK;
  int* cntF = cnt;

  k_init<<<gN, 256, 0, stream>>>(mark1w, mark2, cnt, gcur, WW, bW, W1, W2, b1, N);
  k_firstsel<<<1, 1024, 0, stream>>>(batch, sel, mark1w, mark2, B, NC);
  k_bkt<<<gB, 1024, 0, stream>>>(srcI, dstI, ew, mark1w, mark2, gcur, bktbuf, CAP, E);
  k_degscat<<<NBKT, 256, 0, stream>>>(gcur, bktbuf, CAP, mark2, cntF, fidx, list,
                                      dinv, counts2, fcols, fvals, N);
  k_agg<<<2048, 256, 0, stream>>>(x, list, cntF, counts2, fcols, fvals, dinv, aggx);
  k_h2out<<<B, 128, 0, stream>>>(aggx, sel, fidx, counts2, fcols, fvals, dinv,
                                 WW, bW, b2, (float*)d_out, B);
}

// Round 13
// 99.502 us; speedup vs baseline: 1.7296x; 1.2326x over previous
//
#include <hip/hip_runtime.h>
#include <climits>

// ---------------------------------------------------------------------------
// GCN 2-layer + graclus pooling, frontier-restricted (~8.7k nodes).
// Algebra: h2 = (A^2 x)(W1 W2) + (A 1)(b1 W2) + b2  -> no per-node h1 needed.
//   k_init    : init (incl. first[]=INT_MAX) + (blocks 0-2) WW=W1@W2, bW=b1@W2.
//   k_firstsel: PARALLEL boundary detect on sorted batch; boundary thread owns
//               graph b: first[b]=c, marks nodes 2c,2c+1. Fallback N-2,N-1
//               always marked (absent-graph clamp path). No sel[] array.
//   k_bkt     : full-E pass; 256-node buckets (dst>>8), direct global scatter.
//   k_degscat : 391 blocks x 256 thr: local compact -> fidx/list, LDS degree
//               -> dinv, frontier-edge capture -> fixed-stride CSR.
//   k_agg     : wave/row, float4 half-wave gathers, 16-edge tier (8 in flight).
//   k_h2out   : nodes from first[b]; 8-edge tier; @WW + s*bW + b2; max; out.
// No per-edge device atomics anywhere.
// ---------------------------------------------------------------------------

#define NF_CAP 40960
#define CHUNK 8192         // edges per k_bkt block (1024 thr x 8)
#define STRIDE 128         // max in-degree bound
#define BK_BITS 8          // 256-node buckets
#define NBMAX 512          // padded bucket count (>= NBKT=391)
#define MAXW 3200          // mark1 bitset words for N<=102400

__global__ void k_init(unsigned int* mark1w, unsigned char* mark2,
                       int* first, int* cnt, int* gcur, float* WW, float* bW,
                       const float* __restrict__ W1, const float* __restrict__ W2,
                       const float* __restrict__ b1, int n, int nb) {
  int i = blockIdx.x * blockDim.x + threadIdx.x;
  if (i < n) mark2[i] = 0;
  if (i < MAXW) mark1w[i] = 0;
  if (i < nb) first[i] = INT_MAX;
  if (i < 4) cnt[i] = 0;
  if (i < NBMAX) gcur[i] = 0;
  int t = threadIdx.x;
  int lane = t & 63, wv = t >> 6;
  if (blockIdx.x < 2) {                       // WW = W1(128x64) @ W2(64x64)
    int k0 = blockIdx.x * 64 + wv * 16;
#pragma unroll 1
    for (int k = k0; k < k0 + 16; ++k) {
      float acc = 0.f;
#pragma unroll 8
      for (int m = 0; m < 64; ++m)
        acc += W1[k * 64 + m] * W2[m * 64 + lane];
      WW[k * 64 + lane] = acc;
    }
  } else if (blockIdx.x == 2 && wv == 0) {    // bW = b1 @ W2
    float acc = 0.f;
#pragma unroll 8
    for (int m = 0; m < 64; ++m)
      acc += b1[m] * W2[m * 64 + lane];
    bW[lane] = acc;
  }
}

// parallel: batch sorted -> boundary thread owns graph b (unique writer)
__global__ void k_firstsel(const int* __restrict__ batch, int* first,
                           unsigned int* mark1w, unsigned char* mark2,
                           int nc, int n) {
  int c = blockIdx.x * blockDim.x + threadIdx.x;
  if (c == 0) {                  // fallback nodes for empty-graph clamp path
    mark2[n - 2] = 1; mark2[n - 1] = 1;
    atomicOr(&mark1w[(n - 2) >> 5], 1u << ((n - 2) & 31));
    atomicOr(&mark1w[(n - 1) >> 5], 1u << ((n - 1) & 31));
  }
  if (c >= nc) return;
  int b = batch[2 * c];
  if (c == 0 || batch[2 * c - 2] != b) {
    first[b] = c;                // unique boundary per present graph
    int n0 = 2 * c;
    mark2[n0] = 1; mark2[n0 + 1] = 1;
    atomicOr(&mark1w[n0 >> 5], 3u << (n0 & 31));   // n0 even: both bits in word
  }
}

// --- pass 1: bucket edges by dst>>8; direct global scatter -------------------
__global__ __launch_bounds__(1024) void k_bkt(const int* __restrict__ src,
    const int* __restrict__ dst, const float* __restrict__ w,
    const unsigned int* __restrict__ mark1w, unsigned char* mark2,
    int* gcur, uint2* bktbuf, int cap, int e) {
  __shared__ int scnt[NBMAX], sgb[NBMAX];
  int t = threadIdx.x;
  if (t < NBMAX) scnt[t] = 0;
  __syncthreads();
  int i0 = blockIdx.x * CHUNK;
  int rd[8], rs[8];
  float rw[8];
#pragma unroll
  for (int k = 0; k < 8; ++k) {
    int i = i0 + t + k * 1024;
    if (i < e) {
      int d = dst[i];
      int s = src[i];
      rd[k] = d; rs[k] = s; rw[k] = w[i];
      atomicAdd(&scnt[d >> BK_BITS], 1);
      if ((mark1w[d >> 5] >> (d & 31)) & 1u) mark2[s] = 1;  // L1-resident test
    } else {
      rd[k] = -1;
    }
  }
  __syncthreads();
  if (t < NBMAX) {
    int c = scnt[t];
    sgb[t] = c ? atomicAdd(&gcur[t], c) : 0;
    scnt[t] = 0;                               // same-thread reset: no race
  }
  __syncthreads();
#pragma unroll
  for (int k = 0; k < 8; ++k) {
    if (rd[k] >= 0) {
      int b = rd[k] >> BK_BITS;
      int pos = sgb[b] + atomicAdd(&scnt[b], 1);
      if (pos < cap)
        bktbuf[(size_t)b * cap + pos] =
            make_uint2(((unsigned int)rs[k] << BK_BITS) | (unsigned int)(rd[k] & 255),
                       __float_as_uint(rw[k]));
    }
  }
}

// --- pass 2: per-bucket compact + degree -> dinv + frontier-edge capture -----
__global__ __launch_bounds__(256) void k_degscat(const int* __restrict__ gcur,
    const uint2* __restrict__ bktbuf, int cap, const unsigned char* __restrict__ mark2,
    int* cntF, int* fidx, int* list,
    float* dinv, int* counts2, int* fcols, float* fvals, int n) {
  __shared__ float acc[256];
  __shared__ int sfidx[256];
  __shared__ int lcur[256];
  __shared__ int sd[256];
  __shared__ int base_s;
  int t = threadIdx.x, b = blockIdx.x;
  int gbase = b << BK_BITS;
  int i = gbase + t;
  acc[t] = 0.f;
  int flag = (i < n && mark2[i]) ? 1 : 0;
  sd[t] = flag;
  __syncthreads();
  for (int off = 1; off < 256; off <<= 1) {
    int a = (t >= off) ? sd[t - off] : 0;
    __syncthreads();
    sd[t] += a;
    __syncthreads();
  }
  int incl = sd[t];
  if (t == 255) base_s = atomicAdd(cntF, incl);
  __syncthreads();
  int f0 = -1;
  if (flag) {
    int g = base_s + incl - 1;
    if (g < NF_CAP) { f0 = g; fidx[i] = g; list[g] = i; }
  }
  sfidx[t] = f0;
  lcur[t] = (f0 >= 0) ? f0 * STRIDE : 0;
  __syncthreads();
  int m = min(gcur[b], cap);
  const uint2* base = bktbuf + (size_t)b * cap;
  for (int j = t; j < m; j += 256) {
    uint2 u = base[j];
    int dl = (int)(u.x & 255u);
    float wv = __uint_as_float(u.y);
    atomicAdd(&acc[dl], wv);                      // LDS fp32 atomic
    int f = sfidx[dl];
    if (f >= 0) {
      int pos = atomicAdd(&lcur[dl], 1);          // LDS cursor
      if (pos < (f + 1) * STRIDE) {
        fcols[pos] = (int)(u.x >> BK_BITS);
        fvals[pos] = wv;                          // RAW w; dinv applied later
      }
    }
  }
  __syncthreads();
  if (i < n) {
    dinv[i] = rsqrtf(1.0f + acc[t]);              // +1 = self-loop
    int f = sfidx[t];
    if (f >= 0) counts2[f] = min(lcur[t] - f * STRIDE, STRIDE);
  }
}

// --- aggregation at frontier rows: float4 half-wave, 16-edge deep MLP --------
__global__ __launch_bounds__(256) void k_agg(const float* __restrict__ x,
    const int* __restrict__ list, const int* __restrict__ cntF,
    const int* __restrict__ counts2, const int* __restrict__ fcols,
    const float* __restrict__ fvals, const float* __restrict__ dinv,
    float* __restrict__ aggx) {
  int lane = threadIdx.x & 63;
  int half = lane >> 5, sub = lane & 31;
  int wid = (blockIdx.x * blockDim.x + threadIdx.x) >> 6;
  int nw = (gridDim.x * blockDim.x) >> 6;
  int m = min(*cntF, NF_CAP);
  const float4* x4 = (const float4*)x;      // row i = x4[i*32 + sub]
  float4* a4 = (float4*)aggx;
  for (int li = wid; li < m; li += nw) {
    int i = list[li];
    float dv = dinv[i];
    float4 xi = x4[(size_t)i * 32 + sub];
    float ax = 0.f, ay = 0.f, az = 0.f, aw = 0.f;
    int p = li * STRIDE;
    int end = p + counts2[li];
    while (p + 16 <= end) {                 // 16 edges: 8 gathers/lane in flight
      int c[8]; float v[8]; float4 g[8];
#pragma unroll
      for (int j = 0; j < 8; ++j) {
        c[j] = fcols[p + 2 * j + half];
        v[j] = fvals[p + 2 * j + half];
      }
#pragma unroll
      for (int j = 0; j < 8; ++j) g[j] = x4[(size_t)c[j] * 32 + sub];
#pragma unroll
      for (int j = 0; j < 8; ++j) v[j] *= dinv[c[j]];
#pragma unroll
      for (int j = 0; j < 8; ++j) {
        ax += v[j] * g[j].x; ay += v[j] * g[j].y;
        az += v[j] * g[j].z; aw += v[j] * g[j].w;
      }
      p += 16;
    }
    while (p + 4 <= end) {                  // 4 edges: 2/lane in flight
      int c0 = fcols[p + half], c1 = fcols[p + 2 + half];
      float v0 = fvals[p + half], v1 = fvals[p + 2 + half];
      float4 g0 = x4[(size_t)c0 * 32 + sub];
      float4 g1 = x4[(size_t)c1 * 32 + sub];
      v0 *= dinv[c0]; v1 *= dinv[c1];
      ax += v0 * g0.x + v1 * g1.x; ay += v0 * g0.y + v1 * g1.y;
      az += v0 * g0.z + v1 * g1.z; aw += v0 * g0.w + v1 * g1.w;
      p += 4;
    }
    while (p + 2 <= end) {                  // 2 edges (one per half)
      int c = fcols[p + half];
      float v = fvals[p + half] * dinv[c];
      float4 g = x4[(size_t)c * 32 + sub];
      ax += v * g.x; ay += v * g.y; az += v * g.z; aw += v * g.w;
      p += 2;
    }
    if (p < end && half == 0) {             // odd tail edge
      int c = fcols[p];
      float v = fvals[p] * dinv[c];
      float4 g = x4[(size_t)c * 32 + sub];
      ax += v * g.x; ay += v * g.y; az += v * g.z; aw += v * g.w;
    }
    ax += __shfl(ax, lane ^ 32);            // combine halves
    ay += __shfl(ay, lane ^ 32);
    az += __shfl(az, lane ^ 32);
    aw += __shfl(aw, lane ^ 32);
    if (half == 0) {
      float4 r;
      r.x = dv * (ax + dv * xi.x);
      r.y = dv * (ay + dv * xi.y);
      r.z = dv * (az + dv * xi.z);
      r.w = dv * (aw + dv * xi.w);
      a4[(size_t)li * 32 + sub] = r;
    }
  }
}

// --- fused: aggregate aggx at sel nodes (from first[]), @WW+s*bW+b2, max -----
__global__ __launch_bounds__(128) void k_h2out(const float* __restrict__ aggx,
    const int* __restrict__ first, const int* __restrict__ fidx,
    const int* __restrict__ counts2, const int* __restrict__ fcols,
    const float* __restrict__ fvals, const float* __restrict__ dinv,
    const float* __restrict__ WW, const float* __restrict__ bW,
    const float* __restrict__ b2, float* __restrict__ out, int nb, int nc) {
  __shared__ float Wl[128 * 64];            // 32 KB
  __shared__ float sag[2][128];
  __shared__ float hh[2][64];
  int t = threadIdx.x;
  for (int p = t; p < 128 * 16; p += 128)
    ((float4*)Wl)[p] = ((const float4*)WW)[p];
  __syncthreads();
  int lane = t & 63, wv = t >> 6;
  int half = lane >> 5, sub = lane & 31;
  int b = blockIdx.x;
  if (b >= nb) return;
  int fc = min(first[b], nc - 1);           // JAX gather clamp (empty graph)
  int node = 2 * fc + wv;
  int f = fidx[node];
  float dv = dinv[node];
  const float4* a4 = (const float4*)aggx;
  float ax = 0.f, ay = 0.f, az = 0.f, aw = 0.f, sv = 0.f;
  int p = f * STRIDE;
  int end = p + counts2[f];
  while (p + 8 <= end) {                    // 8 edges: 4 gathers/lane in flight
    int c[4]; float v[4]; int g[4]; float4 r[4];
#pragma unroll
    for (int j = 0; j < 4; ++j) {
      c[j] = fcols[p + 2 * j + half];
      v[j] = fvals[p + 2 * j + half];
    }
#pragma unroll
    for (int j = 0; j < 4; ++j) g[j] = fidx[c[j]];
#pragma unroll
    for (int j = 0; j < 4; ++j) v[j] *= dinv[c[j]];
#pragma unroll
    for (int j = 0; j < 4; ++j) r[j] = a4[(size_t)g[j] * 32 + sub];
#pragma unroll
    for (int j = 0; j < 4; ++j) {
      ax += v[j] * r[j].x; ay += v[j] * r[j].y;
      az += v[j] * r[j].z; aw += v[j] * r[j].w;
      sv += v[j];
    }
    p += 8;
  }
  while (p + 2 <= end) {
    int c = fcols[p + half];
    float v = fvals[p + half] * dinv[c];
    int g = fidx[c];
    float4 r = a4[(size_t)g * 32 + sub];
    ax += v * r.x; ay += v * r.y; az += v * r.z; aw += v * r.w;
    sv += v;
    p += 2;
  }
  if (p < end && half == 0) {
    int c = fcols[p];
    float v = fvals[p] * dinv[c];
    int g = fidx[c];
    float4 r = a4[(size_t)g * 32 + sub];
    ax += v * r.x; ay += v * r.y; az += v * r.z; aw += v * r.w;
    sv += v;
  }
  ax += __shfl(ax, lane ^ 32);
  ay += __shfl(ay, lane ^ 32);
  az += __shfl(az, lane ^ 32);
  aw += __shfl(aw, lane ^ 32);
  sv += __shfl(sv, lane ^ 32);
  float4 rs = a4[(size_t)f * 32 + sub];
  if (half == 0) {
    sag[wv][4 * sub + 0] = dv * (ax + dv * rs.x);
    sag[wv][4 * sub + 1] = dv * (ay + dv * rs.y);
    sag[wv][4 * sub + 2] = dv * (az + dv * rs.z);
    sag[wv][4 * sub + 3] = dv * (aw + dv * rs.w);
  }
  float sfin = dv * (sv + dv);              // (A 1)[node]
  __syncthreads();
  float o = b2[lane] + sfin * bW[lane];
#pragma unroll 8
  for (int k = 0; k < 128; ++k)
    o += sag[wv][k] * Wl[k * 64 + lane];
  hh[wv][lane] = o;
  __syncthreads();
  if (wv == 0)
    out[(size_t)b * 64 + lane] = fmaxf(hh[0][lane], hh[1][lane]);
}

extern "C" void kernel_launch(void* const* d_in, const int* in_sizes, int n_in,
                              void* d_out, int out_size, void* d_ws, size_t ws_size,
                              hipStream_t stream) {
  const float* x     = (const float*)d_in[0];
  const int*   ei    = (const int*)d_in[1];
  const float* ew    = (const float*)d_in[2];
  const int*   batch = (const int*)d_in[3];
  const float* W1    = (const float*)d_in[4];
  const float* b1    = (const float*)d_in[5];
  const float* W2    = (const float*)d_in[6];
  const float* b2    = (const float*)d_in[7];

  const int E  = in_sizes[2];
  const int N  = in_sizes[3];
  const int B  = out_size / 64;
  const int NC = N / 2;
  const int* srcI = ei;
  const int* dstI = ei + E;

  const int NBKT = (N + 255) >> BK_BITS;            // 391 for N=100k
  const int CAP  = ((E + NBKT - 1) / NBKT) * 2;     // ~2x expected bucket load

  char* p = (char*)d_ws;
  auto alloc = [&](size_t bytes) -> char* {
    char* r = p;
    p += (bytes + 255) & ~size_t(255);
    return r;
  };
  float* dinv    = (float*)alloc((size_t)N * 4);
  unsigned int* mark1w = (unsigned int*)alloc((size_t)MAXW * 4);
  unsigned char* mark2 = (unsigned char*)alloc(N);
  int*   fidx    = (int*)alloc((size_t)N * 4);
  int*   list    = (int*)alloc((size_t)NF_CAP * 4);
  int*   counts2 = (int*)alloc((size_t)NF_CAP * 4);
  int*   first   = (int*)alloc((size_t)B * 4);
  int*   cnt     = (int*)alloc(256);                // [0]=cntF
  int*   gcur    = (int*)alloc(NBMAX * 4);
  float* WW      = (float*)alloc(128 * 64 * 4);
  float* bW      = (float*)alloc(64 * 4);
  uint2* bktbuf  = (uint2*)alloc((size_t)NBKT * CAP * 8);
  int*   fcols   = (int*)alloc((size_t)NF_CAP * STRIDE * 4);
  float* fvals   = (float*)alloc((size_t)NF_CAP * STRIDE * 4);
  float* aggx    = (float*)alloc((size_t)NF_CAP * 128 * 4);

  int gN = (N + 255) / 256;
  int gB = (E + CHUNK - 1) / CHUNK;
  int* cntF = cnt;

  k_init<<<gN, 256, 0, stream>>>(mark1w, mark2, first, cnt, gcur, WW, bW,
                                 W1, W2, b1, N, B);
  k_firstsel<<<(NC + 255) / 256, 256, 0, stream>>>(batch, first, mark1w, mark2, NC, N);
  k_bkt<<<gB, 1024, 0, stream>>>(srcI, dstI, ew, mark1w, mark2, gcur, bktbuf, CAP, E);
  k_degscat<<<NBKT, 256, 0, stream>>>(gcur, bktbuf, CAP, mark2, cntF, fidx, list,
                                      dinv, counts2, fcols, fvals, N);
  k_agg<<<2048, 256, 0, stream>>>(x, list, cntF, counts2, fcols, fvals, dinv, aggx);
  k_h2out<<<B, 128, 0, stream>>>(aggx, first, fidx, counts2, fcols, fvals, dinv,
                                 WW, bW, b2, (float*)d_out, B, NC);
}